// Round 1
// baseline (4725.114 us; speedup 1.0000x reference)
//
#include <hip/hip_runtime.h>

// ---------------- small kernels ----------------

__global__ void k_zero_int(int* __restrict__ p, int n) {
    int i = blockIdx.x * 256 + threadIdx.x;
    if (i < n) p[i] = 0;
}

__global__ void k_deg(const int* __restrict__ dst, int* __restrict__ deg, int E) {
    int e = blockIdx.x * 256 + threadIdx.x;
    if (e < E) atomicAdd(&deg[dst[e]], 1);
}

__global__ void k_dinv(const int* __restrict__ deg, float* __restrict__ dinv, int N) {
    int i = blockIdx.x * 256 + threadIdx.x;
    if (i < N) dinv[i] = rsqrtf((float)(deg[i] + 1));  // +1 self-loop
}

__global__ void k_norm(const int* __restrict__ ei, const float* __restrict__ dinv,
                       float* __restrict__ nrm, int E) {
    int e = blockIdx.x * 256 + threadIdx.x;
    if (e < E) nrm[e] = dinv[ei[e]] * dinv[ei[E + e]];
}

// out[i,:] = in[i,:] * dinv[i]^2   (self-loop contribution; also inits buffer)
template<int F>
__global__ void k_selfloop(const float* __restrict__ in, const float* __restrict__ dinv,
                           float* __restrict__ out, int N) {
    int idx = blockIdx.x * 256 + threadIdx.x;
    int per = F / 4;
    if (idx >= N * per) return;
    int row = idx / per;
    float d = dinv[row]; d *= d;
    float4 v = ((const float4*)in)[idx];
    v.x *= d; v.y *= d; v.z *= d; v.w *= d;
    ((float4*)out)[idx] = v;
}

// out[dst,:] += in[src,:] * norm[e]
template<int F>
__global__ void k_scatter(const int* __restrict__ ei, const float* __restrict__ nrm,
                          const float* __restrict__ in, float* __restrict__ out, int E) {
    int idx = blockIdx.x * 256 + threadIdx.x;
    const int per = F / 4;
    if (idx >= E * per) return;
    int e = idx / per, c4 = idx % per;
    int s = ei[e], d = ei[E + e];
    float nm = nrm[e];
    float4 v = ((const float4*)(in + (size_t)s * F))[c4];
    float* o = out + (size_t)d * F + c4 * 4;
    atomicAdd(o + 0, v.x * nm);
    atomicAdd(o + 1, v.y * nm);
    atomicAdd(o + 2, v.z * nm);
    atomicAdd(o + 3, v.w * nm);
}

template<int F>
__global__ void k_bias_relu(float* __restrict__ x, const float* __restrict__ b, int N) {
    int idx = blockIdx.x * 256 + threadIdx.x;
    const int per = F / 4;
    if (idx >= N * per) return;
    int c4 = idx % per;
    float4 v = ((float4*)x)[idx];
    float4 bb = ((const float4*)b)[c4];
    v.x = fmaxf(v.x + bb.x, 0.f);
    v.y = fmaxf(v.y + bb.y, 0.f);
    v.z = fmaxf(v.z + bb.z, 0.f);
    v.w = fmaxf(v.w + bb.w, 0.f);
    ((float4*)x)[idx] = v;
}

// ---------------- tiled fp32 GEMM: Y[N,F] = X[N,K] @ W[K,F] (+bias)(relu) ----------------

template<bool BIAS, bool RELU>
__global__ __launch_bounds__(256) void k_gemm(const float* __restrict__ X,
                                              const float* __restrict__ W,
                                              const float* __restrict__ bias,
                                              float* __restrict__ Y,
                                              int N, int K, int F) {
    __shared__ float Xs[64][33];
    __shared__ float Ws[32][65];
    int t = threadIdx.x;
    int row0 = blockIdx.x * 64;
    int col0 = blockIdx.y * 64;
    int tx = t & 15, ty = t >> 4;
    float acc[4][4] = {};
    for (int kc = 0; kc < K; kc += 32) {
#pragma unroll
        for (int i = 0; i < 8; i++) {
            int flat = t + i * 256;
            int r = flat >> 5, kk = flat & 31;
            int gr = row0 + r, gk = kc + kk;
            Xs[r][kk] = (gr < N && gk < K) ? X[(size_t)gr * K + gk] : 0.f;
        }
#pragma unroll
        for (int i = 0; i < 8; i++) {
            int flat = t + i * 256;
            int kk = flat >> 6, c = flat & 63;
            int gk = kc + kk, gc = col0 + c;
            Ws[kk][c] = (gk < K && gc < F) ? W[(size_t)gk * F + gc] : 0.f;
        }
        __syncthreads();
#pragma unroll
        for (int kk = 0; kk < 32; kk++) {
            float a[4], b[4];
#pragma unroll
            for (int i = 0; i < 4; i++) a[i] = Xs[ty * 4 + i][kk];
#pragma unroll
            for (int j = 0; j < 4; j++) b[j] = Ws[kk][tx * 4 + j];
#pragma unroll
            for (int i = 0; i < 4; i++)
#pragma unroll
                for (int j = 0; j < 4; j++)
                    acc[i][j] += a[i] * b[j];
        }
        __syncthreads();
    }
#pragma unroll
    for (int i = 0; i < 4; i++) {
        int gr = row0 + ty * 4 + i;
        if (gr >= N) continue;
#pragma unroll
        for (int j = 0; j < 4; j++) {
            int gc = col0 + tx * 4 + j;
            if (gc >= F) continue;
            float v = acc[i][j];
            if (BIAS) v += bias[gc];
            if (RELU) v = fmaxf(v, 0.f);
            Y[(size_t)gr * F + gc] = v;
        }
    }
}

// ---------------- layer-3 GEMM fused with per-graph mean pool ----------------
// Each block: 2 graphs (60 rows, 4 pad) x 64 cols of relu(X@W3+b3), then
// reduce 30 rows per graph -> pooled mean [8192 x 256]. K=128, F=256.
__global__ __launch_bounds__(256) void k_gemm_pool(const float* __restrict__ X,
                                                   const float* __restrict__ W,
                                                   const float* __restrict__ bias,
                                                   float* __restrict__ P) {
    __shared__ float Xs[64][33];
    __shared__ float Ws[32][65];
    __shared__ float Ts[64][65];
    const int K = 128, F = 256;
    int t = threadIdx.x;
    int bg = blockIdx.x;                // graph pair
    int col0 = blockIdx.y * 64;
    size_t rbase = (size_t)bg * 60;
    int tx = t & 15, ty = t >> 4;
    float acc[4][4] = {};
    for (int kc = 0; kc < K; kc += 32) {
#pragma unroll
        for (int i = 0; i < 8; i++) {
            int flat = t + i * 256;
            int r = flat >> 5, kk = flat & 31;
            Xs[r][kk] = (r < 60) ? X[(rbase + r) * K + kc + kk] : 0.f;
        }
#pragma unroll
        for (int i = 0; i < 8; i++) {
            int flat = t + i * 256;
            int kk = flat >> 6, c = flat & 63;
            Ws[kk][c] = W[(size_t)(kc + kk) * F + col0 + c];
        }
        __syncthreads();
#pragma unroll
        for (int kk = 0; kk < 32; kk++) {
            float a[4], b[4];
#pragma unroll
            for (int i = 0; i < 4; i++) a[i] = Xs[ty * 4 + i][kk];
#pragma unroll
            for (int j = 0; j < 4; j++) b[j] = Ws[kk][tx * 4 + j];
#pragma unroll
            for (int i = 0; i < 4; i++)
#pragma unroll
                for (int j = 0; j < 4; j++)
                    acc[i][j] += a[i] * b[j];
        }
        __syncthreads();
    }
#pragma unroll
    for (int i = 0; i < 4; i++)
#pragma unroll
        for (int j = 0; j < 4; j++)
            Ts[ty * 4 + i][tx * 4 + j] = fmaxf(acc[i][j] + bias[col0 + tx * 4 + j], 0.f);
    __syncthreads();
    if (t < 128) {
        int g = t >> 6, c = t & 63;
        float s = 0.f;
#pragma unroll
        for (int r = 0; r < 30; r++) s += Ts[g * 30 + r][c];
        P[((size_t)bg * 2 + g) * F + col0 + c] = s * (1.0f / 30.0f);
    }
}

// ---------------- combiner head: per-graph tiny MLP ----------------
__global__ __launch_bounds__(64) void k_head(const float* __restrict__ drug,
                                             const float* __restrict__ cell,
                                             const float* __restrict__ Wm1, const float* __restrict__ bm1,
                                             const float* __restrict__ Wm2, const float* __restrict__ bm2,
                                             const float* __restrict__ Wo, const float* __restrict__ bo,
                                             float* __restrict__ out) {
    __shared__ float comb[128];
    __shared__ float z1[64];
    __shared__ float z2[32];
    int g = blockIdx.x, t = threadIdx.x;
    comb[t] = drug[(size_t)g * 64 + t];
    comb[64 + t] = cell[(size_t)g * 64 + t];
    __syncthreads();
    float s = bm1[t];
#pragma unroll 8
    for (int k = 0; k < 128; k++) s += comb[k] * Wm1[k * 64 + t];
    z1[t] = fmaxf(s, 0.f);
    __syncthreads();
    if (t < 32) {
        float s2 = bm2[t];
#pragma unroll 8
        for (int k = 0; k < 64; k++) s2 += z1[k] * Wm2[k * 32 + t];
        z2[t] = fmaxf(s2, 0.f);
    }
    __syncthreads();
    float v = (t < 32) ? z2[t] * Wo[t] : 0.f;
#pragma unroll
    for (int off = 32; off > 0; off >>= 1) v += __shfl_down(v, off);
    if (t == 0) out[g] = v + bo[0];
}

// ---------------- launch ----------------

extern "C" void kernel_launch(void* const* d_in, const int* in_sizes, int n_in,
                              void* d_out, int out_size, void* d_ws, size_t ws_size,
                              hipStream_t stream) {
    const float* x   = (const float*)d_in[0];
    const int*   ei  = (const int*)d_in[1];
    const float* cf  = (const float*)d_in[3];
    const float* W1  = (const float*)d_in[4];
    const float* b1  = (const float*)d_in[5];
    const float* W2  = (const float*)d_in[6];
    const float* b2  = (const float*)d_in[7];
    const float* W3  = (const float*)d_in[8];
    const float* b3  = (const float*)d_in[9];
    const float* Wd  = (const float*)d_in[10];
    const float* bd  = (const float*)d_in[11];
    const float* Wc1 = (const float*)d_in[12];
    const float* bc1 = (const float*)d_in[13];
    const float* Wc2 = (const float*)d_in[14];
    const float* bc2 = (const float*)d_in[15];
    const float* Wm1 = (const float*)d_in[16];
    const float* bm1 = (const float*)d_in[17];
    const float* Wm2 = (const float*)d_in[18];
    const float* bm2 = (const float*)d_in[19];
    const float* Wo  = (const float*)d_in[20];
    const float* bo  = (const float*)d_in[21];
    float* out = (float*)d_out;

    const int N = in_sizes[0] / 78;    // 245760
    const int E = in_sizes[1] / 2;     // 1,000,000
    const int B = in_sizes[3] / 1000;  // 8192

    // workspace carve
    char* w = (char*)d_ws;
    auto carve = [&](size_t bytes) { void* p = (void*)w; w += (bytes + 255) & ~(size_t)255; return p; };
    int*   deg    = (int*)  carve((size_t)N * 4);
    float* dinv   = (float*)carve((size_t)N * 4);
    float* nrm    = (float*)carve((size_t)E * 4);
    float* pooled = (float*)carve((size_t)B * 256 * 4);
    float* drug   = (float*)carve((size_t)B * 64 * 4);
    float* cell1  = (float*)carve((size_t)B * 128 * 4);
    float* cell2  = (float*)carve((size_t)B * 64 * 4);
    float* bufA   = (float*)carve((size_t)N * 128 * 4);
    float* bufB   = (float*)carve((size_t)N * 128 * 4);

    auto g1 = [](int n) { return (n + 255) / 256; };

    // degrees + norms
    k_zero_int<<<g1(N), 256, 0, stream>>>(deg, N);
    k_deg<<<g1(E), 256, 0, stream>>>(ei + E, deg, E);
    k_dinv<<<g1(N), 256, 0, stream>>>(deg, dinv, N);
    k_norm<<<g1(E), 256, 0, stream>>>(ei, dinv, nrm, E);

    // layer 1: t1 = x@W1 ; h1 = relu(A@t1 + b1)
    k_gemm<false, false><<<dim3(N / 64, 1), 256, 0, stream>>>(x, W1, nullptr, bufA, N, 78, 64);
    k_selfloop<64><<<g1(N * 16), 256, 0, stream>>>(bufA, dinv, bufB, N);
    k_scatter<64><<<g1(E * 16), 256, 0, stream>>>(ei, nrm, bufA, bufB, E);
    k_bias_relu<64><<<g1(N * 16), 256, 0, stream>>>(bufB, b1, N);

    // layer 2: a2 = A@h1 ; h2 = relu(a2@W2 + b2)
    k_selfloop<64><<<g1(N * 16), 256, 0, stream>>>(bufB, dinv, bufA, N);
    k_scatter<64><<<g1(E * 16), 256, 0, stream>>>(ei, nrm, bufB, bufA, E);
    k_gemm<true, true><<<dim3(N / 64, 2), 256, 0, stream>>>(bufA, W2, b2, bufB, N, 64, 128);

    // layer 3: a3 = A@h2 ; pooled = mean_graph relu(a3@W3 + b3)
    k_selfloop<128><<<g1(N * 32), 256, 0, stream>>>(bufB, dinv, bufA, N);
    k_scatter<128><<<g1(E * 32), 256, 0, stream>>>(ei, nrm, bufB, bufA, E);
    k_gemm_pool<<<dim3(B / 2, 4), 256, 0, stream>>>(bufA, W3, b3, pooled);

    // drug = pooled @ Wd + bd
    k_gemm<true, false><<<dim3(B / 64, 1), 256, 0, stream>>>(pooled, Wd, bd, drug, B, 256, 64);

    // cell MLP
    k_gemm<true, true><<<dim3(B / 64, 2), 256, 0, stream>>>(cf, Wc1, bc1, cell1, B, 1000, 128);
    k_gemm<true, false><<<dim3(B / 64, 1), 256, 0, stream>>>(cell1, Wc2, bc2, cell2, B, 128, 64);

    // combiner head
    k_head<<<B, 64, 0, stream>>>(drug, cell2, Wm1, bm1, Wm2, bm2, Wo, bo, out);
}

// Round 2
// 1561.576 us; speedup vs baseline: 3.0259x; 3.0259x over previous
//
#include <hip/hip_runtime.h>

// ---------------- small kernels ----------------

__global__ void k_zero_int(int* __restrict__ p, int n) {
    int i = blockIdx.x * 256 + threadIdx.x;
    if (i < n) p[i] = 0;
}

__global__ void k_deg(const int* __restrict__ dst, int* __restrict__ deg, int E) {
    int e = blockIdx.x * 256 + threadIdx.x;
    if (e < E) atomicAdd(&deg[dst[e]], 1);
}

__global__ void k_dinv(const int* __restrict__ deg, float* __restrict__ dinv, int N) {
    int i = blockIdx.x * 256 + threadIdx.x;
    if (i < N) dinv[i] = rsqrtf((float)(deg[i] + 1));  // +1 self-loop
}

// count edges per graph (graph id = dst/30)
__global__ void k_count(const int* __restrict__ dst, int* __restrict__ ecnt, int E) {
    int e = blockIdx.x * 256 + threadIdx.x;
    if (e < E) atomicAdd(&ecnt[dst[e] / 30], 1);
}

// exclusive prefix scan over B=8192 counts, single block of 1024 threads
__global__ __launch_bounds__(1024) void k_scan(const int* __restrict__ ecnt,
                                               int* __restrict__ estart,
                                               int* __restrict__ ecursor) {
    __shared__ int sh[1024];
    int t = threadIdx.x;
    int loc[8]; int sum = 0;
#pragma unroll
    for (int i = 0; i < 8; i++) { loc[i] = ecnt[t * 8 + i]; sum += loc[i]; }
    sh[t] = sum;
    __syncthreads();
    for (int off = 1; off < 1024; off <<= 1) {
        int v = (t >= off) ? sh[t - off] : 0;
        __syncthreads();
        sh[t] += v;
        __syncthreads();
    }
    int run = sh[t] - sum;  // exclusive prefix of this thread's chunk
#pragma unroll
    for (int i = 0; i < 8; i++) {
        estart[t * 8 + i] = run;
        ecursor[t * 8 + i] = run;
        run += loc[i];
    }
}

// reorder edges into per-graph buckets, packed as u16: src_local | dst_local<<5
__global__ void k_bucket(const int* __restrict__ ei, int* __restrict__ ecursor,
                         unsigned short* __restrict__ sE, int E) {
    int e = blockIdx.x * 256 + threadIdx.x;
    if (e >= E) return;
    int s = ei[e], d = ei[E + e];
    int g = d / 30;
    int p = atomicAdd(&ecursor[g], 1);
    sE[p] = (unsigned short)((s - g * 30) | ((d - g * 30) << 5));
}

// ---------------- per-graph LDS aggregation ----------------
// out[i] = dinv[i]^2 * in[i] + sum_{e:(s->i)} dinv[s]*dinv[i]*in[s]
// Block handles NG graphs (NG*F == 256). Thread owns (graph, column):
// sequential edge walk per column -> no atomics, no races.
template<int F, int NG, bool EPI>
__global__ __launch_bounds__(256) void k_agg(const float* __restrict__ in,
                                             const float* __restrict__ dinv,
                                             const unsigned short* __restrict__ sE,
                                             const int* __restrict__ estart,
                                             const int* __restrict__ ecnt,
                                             const float* __restrict__ bias,
                                             float* __restrict__ outp) {
    __shared__ float in_l[NG * 30 * F];
    __shared__ float out_l[NG * 30 * F];
    __shared__ float dv[NG * 30];
    int t = threadIdx.x;
    int g0 = blockIdx.x * NG;
    size_t base = (size_t)g0 * 30 * F;
    const int TOT4 = NG * 30 * F / 4;
    const float4* gin = (const float4*)(in + base);
    for (int i = t; i < TOT4; i += 256) ((float4*)in_l)[i] = gin[i];
    if (t < NG * 30) dv[t] = dinv[g0 * 30 + t];
    __syncthreads();

    int gi = t / F;
    int c = t % F;
    // self-loop init
#pragma unroll
    for (int i = 0; i < 30; i++) {
        float d = dv[gi * 30 + i];
        out_l[(gi * 30 + i) * F + c] = in_l[(gi * 30 + i) * F + c] * d * d;
    }
    int g = g0 + gi;
    int cnt = ecnt[g];
    int st = estart[g];
    for (int j = 0; j < cnt; j++) {
        int p = sE[st + j];
        int s = p & 31, d = p >> 5;
        float nm = dv[gi * 30 + s] * dv[gi * 30 + d];
        out_l[(gi * 30 + d) * F + c] += in_l[(gi * 30 + s) * F + c] * nm;
    }
    __syncthreads();

    float* gout = outp + base;
    for (int i = t; i < TOT4; i += 256) {
        float4 v = ((float4*)out_l)[i];
        if (EPI) {
            int cc = (i * 4) % F;
            float4 bb = *(const float4*)(bias + cc);
            v.x = fmaxf(v.x + bb.x, 0.f);
            v.y = fmaxf(v.y + bb.y, 0.f);
            v.z = fmaxf(v.z + bb.z, 0.f);
            v.w = fmaxf(v.w + bb.w, 0.f);
        }
        ((float4*)gout)[i] = v;
    }
}

// ---------------- tiled fp32 GEMM: Y[N,F] = X[N,K] @ W[K,F] (+bias)(relu) ----------------

template<bool BIAS, bool RELU>
__global__ __launch_bounds__(256) void k_gemm(const float* __restrict__ X,
                                              const float* __restrict__ W,
                                              const float* __restrict__ bias,
                                              float* __restrict__ Y,
                                              int N, int K, int F) {
    __shared__ float Xs[64][33];
    __shared__ float Ws[32][65];
    int t = threadIdx.x;
    int row0 = blockIdx.x * 64;
    int col0 = blockIdx.y * 64;
    int tx = t & 15, ty = t >> 4;
    float acc[4][4] = {};
    for (int kc = 0; kc < K; kc += 32) {
#pragma unroll
        for (int i = 0; i < 8; i++) {
            int flat = t + i * 256;
            int r = flat >> 5, kk = flat & 31;
            int gr = row0 + r, gk = kc + kk;
            Xs[r][kk] = (gr < N && gk < K) ? X[(size_t)gr * K + gk] : 0.f;
        }
#pragma unroll
        for (int i = 0; i < 8; i++) {
            int flat = t + i * 256;
            int kk = flat >> 6, c = flat & 63;
            int gk = kc + kk, gc = col0 + c;
            Ws[kk][c] = (gk < K && gc < F) ? W[(size_t)gk * F + gc] : 0.f;
        }
        __syncthreads();
#pragma unroll
        for (int kk = 0; kk < 32; kk++) {
            float a[4], b[4];
#pragma unroll
            for (int i = 0; i < 4; i++) a[i] = Xs[ty * 4 + i][kk];
#pragma unroll
            for (int j = 0; j < 4; j++) b[j] = Ws[kk][tx * 4 + j];
#pragma unroll
            for (int i = 0; i < 4; i++)
#pragma unroll
                for (int j = 0; j < 4; j++)
                    acc[i][j] += a[i] * b[j];
        }
        __syncthreads();
    }
#pragma unroll
    for (int i = 0; i < 4; i++) {
        int gr = row0 + ty * 4 + i;
        if (gr >= N) continue;
#pragma unroll
        for (int j = 0; j < 4; j++) {
            int gc = col0 + tx * 4 + j;
            if (gc >= F) continue;
            float v = acc[i][j];
            if (BIAS) v += bias[gc];
            if (RELU) v = fmaxf(v, 0.f);
            Y[(size_t)gr * F + gc] = v;
        }
    }
}

// ---------------- layer-3 GEMM fused with per-graph mean pool ----------------
__global__ __launch_bounds__(256) void k_gemm_pool(const float* __restrict__ X,
                                                   const float* __restrict__ W,
                                                   const float* __restrict__ bias,
                                                   float* __restrict__ P) {
    __shared__ float Xs[64][33];
    __shared__ float Ws[32][65];
    __shared__ float Ts[64][65];
    const int K = 128, F = 256;
    int t = threadIdx.x;
    int bg = blockIdx.x;                // graph pair
    int col0 = blockIdx.y * 64;
    size_t rbase = (size_t)bg * 60;
    int tx = t & 15, ty = t >> 4;
    float acc[4][4] = {};
    for (int kc = 0; kc < K; kc += 32) {
#pragma unroll
        for (int i = 0; i < 8; i++) {
            int flat = t + i * 256;
            int r = flat >> 5, kk = flat & 31;
            Xs[r][kk] = (r < 60) ? X[(rbase + r) * K + kc + kk] : 0.f;
        }
#pragma unroll
        for (int i = 0; i < 8; i++) {
            int flat = t + i * 256;
            int kk = flat >> 6, c = flat & 63;
            Ws[kk][c] = W[(size_t)(kc + kk) * F + col0 + c];
        }
        __syncthreads();
#pragma unroll
        for (int kk = 0; kk < 32; kk++) {
            float a[4], b[4];
#pragma unroll
            for (int i = 0; i < 4; i++) a[i] = Xs[ty * 4 + i][kk];
#pragma unroll
            for (int j = 0; j < 4; j++) b[j] = Ws[kk][tx * 4 + j];
#pragma unroll
            for (int i = 0; i < 4; i++)
#pragma unroll
                for (int j = 0; j < 4; j++)
                    acc[i][j] += a[i] * b[j];
        }
        __syncthreads();
    }
#pragma unroll
    for (int i = 0; i < 4; i++)
#pragma unroll
        for (int j = 0; j < 4; j++)
            Ts[ty * 4 + i][tx * 4 + j] = fmaxf(acc[i][j] + bias[col0 + tx * 4 + j], 0.f);
    __syncthreads();
    if (t < 128) {
        int g = t >> 6, c = t & 63;
        float s = 0.f;
#pragma unroll
        for (int r = 0; r < 30; r++) s += Ts[g * 30 + r][c];
        P[((size_t)bg * 2 + g) * F + col0 + c] = s * (1.0f / 30.0f);
    }
}

// ---------------- combiner head: per-graph tiny MLP ----------------
__global__ __launch_bounds__(64) void k_head(const float* __restrict__ drug,
                                             const float* __restrict__ cell,
                                             const float* __restrict__ Wm1, const float* __restrict__ bm1,
                                             const float* __restrict__ Wm2, const float* __restrict__ bm2,
                                             const float* __restrict__ Wo, const float* __restrict__ bo,
                                             float* __restrict__ out) {
    __shared__ float comb[128];
    __shared__ float z1[64];
    __shared__ float z2[32];
    int g = blockIdx.x, t = threadIdx.x;
    comb[t] = drug[(size_t)g * 64 + t];
    comb[64 + t] = cell[(size_t)g * 64 + t];
    __syncthreads();
    float s = bm1[t];
#pragma unroll 8
    for (int k = 0; k < 128; k++) s += comb[k] * Wm1[k * 64 + t];
    z1[t] = fmaxf(s, 0.f);
    __syncthreads();
    if (t < 32) {
        float s2 = bm2[t];
#pragma unroll 8
        for (int k = 0; k < 64; k++) s2 += z1[k] * Wm2[k * 32 + t];
        z2[t] = fmaxf(s2, 0.f);
    }
    __syncthreads();
    float v = (t < 32) ? z2[t] * Wo[t] : 0.f;
#pragma unroll
    for (int off = 32; off > 0; off >>= 1) v += __shfl_down(v, off);
    if (t == 0) out[g] = v + bo[0];
}

// ---------------- launch ----------------

extern "C" void kernel_launch(void* const* d_in, const int* in_sizes, int n_in,
                              void* d_out, int out_size, void* d_ws, size_t ws_size,
                              hipStream_t stream) {
    const float* x   = (const float*)d_in[0];
    const int*   ei  = (const int*)d_in[1];
    const float* cf  = (const float*)d_in[3];
    const float* W1  = (const float*)d_in[4];
    const float* b1  = (const float*)d_in[5];
    const float* W2  = (const float*)d_in[6];
    const float* b2  = (const float*)d_in[7];
    const float* W3  = (const float*)d_in[8];
    const float* b3  = (const float*)d_in[9];
    const float* Wd  = (const float*)d_in[10];
    const float* bd  = (const float*)d_in[11];
    const float* Wc1 = (const float*)d_in[12];
    const float* bc1 = (const float*)d_in[13];
    const float* Wc2 = (const float*)d_in[14];
    const float* bc2 = (const float*)d_in[15];
    const float* Wm1 = (const float*)d_in[16];
    const float* bm1 = (const float*)d_in[17];
    const float* Wm2 = (const float*)d_in[18];
    const float* bm2 = (const float*)d_in[19];
    const float* Wo  = (const float*)d_in[20];
    const float* bo  = (const float*)d_in[21];
    float* out = (float*)d_out;

    const int N = in_sizes[0] / 78;    // 245760
    const int E = in_sizes[1] / 2;     // 1,000,000
    const int B = in_sizes[3] / 1000;  // 8192

    // workspace carve
    char* w = (char*)d_ws;
    auto carve = [&](size_t bytes) { void* p = (void*)w; w += (bytes + 255) & ~(size_t)255; return p; };
    int*   deg    = (int*)  carve((size_t)N * 4);
    float* dinv   = (float*)carve((size_t)N * 4);
    int*   ecnt   = (int*)  carve((size_t)B * 4);
    int*   estart = (int*)  carve((size_t)B * 4);
    int*   ecur   = (int*)  carve((size_t)B * 4);
    unsigned short* sE = (unsigned short*)carve((size_t)E * 2);
    float* pooled = (float*)carve((size_t)B * 256 * 4);
    float* drug   = (float*)carve((size_t)B * 64 * 4);
    float* cell1  = (float*)carve((size_t)B * 128 * 4);
    float* cell2  = (float*)carve((size_t)B * 64 * 4);
    float* bufA   = (float*)carve((size_t)N * 128 * 4);
    float* bufB   = (float*)carve((size_t)N * 128 * 4);

    auto g1 = [](int n) { return (n + 255) / 256; };

    // degrees, dinv, edge bucketing
    k_zero_int<<<g1(N), 256, 0, stream>>>(deg, N);
    k_zero_int<<<g1(B), 256, 0, stream>>>(ecnt, B);
    k_deg<<<g1(E), 256, 0, stream>>>(ei + E, deg, E);
    k_count<<<g1(E), 256, 0, stream>>>(ei + E, ecnt, E);
    k_dinv<<<g1(N), 256, 0, stream>>>(deg, dinv, N);
    k_scan<<<1, 1024, 0, stream>>>(ecnt, estart, ecur);
    k_bucket<<<g1(E), 256, 0, stream>>>(ei, ecur, sE, E);

    // layer 1: t1 = x@W1 ; h1 = relu(A@t1 + b1)
    k_gemm<false, false><<<dim3(N / 64, 1), 256, 0, stream>>>(x, W1, nullptr, bufA, N, 78, 64);
    k_agg<64, 4, true><<<B / 4, 256, 0, stream>>>(bufA, dinv, sE, estart, ecnt, b1, bufB);

    // layer 2: a2 = A@h1 ; h2 = relu(a2@W2 + b2)
    k_agg<64, 4, false><<<B / 4, 256, 0, stream>>>(bufB, dinv, sE, estart, ecnt, nullptr, bufA);
    k_gemm<true, true><<<dim3(N / 64, 2), 256, 0, stream>>>(bufA, W2, b2, bufB, N, 64, 128);

    // layer 3: a3 = A@h2 ; pooled = mean_graph relu(a3@W3 + b3)
    k_agg<128, 2, false><<<B / 2, 256, 0, stream>>>(bufB, dinv, sE, estart, ecnt, nullptr, bufA);
    k_gemm_pool<<<dim3(B / 2, 4), 256, 0, stream>>>(bufA, W3, b3, pooled);

    // drug = pooled @ Wd + bd
    k_gemm<true, false><<<dim3(B / 64, 1), 256, 0, stream>>>(pooled, Wd, bd, drug, B, 256, 64);

    // cell MLP
    k_gemm<true, true><<<dim3(B / 64, 2), 256, 0, stream>>>(cf, Wc1, bc1, cell1, B, 1000, 128);
    k_gemm<true, false><<<dim3(B / 64, 1), 256, 0, stream>>>(cell1, Wc2, bc2, cell2, B, 128, 64);

    // combiner head
    k_head<<<B, 64, 0, stream>>>(drug, cell2, Wm1, bm1, Wm2, bm2, Wo, bo, out);
}

// Round 3
// 1374.433 us; speedup vs baseline: 3.4379x; 1.1362x over previous
//
#include <hip/hip_runtime.h>

typedef __attribute__((ext_vector_type(8))) short short8;
typedef __attribute__((ext_vector_type(4))) float f32x4;
typedef unsigned short u16;

__device__ __forceinline__ u16 f2bf(float f) {
    union { float f; unsigned u; } v; v.f = f;
    unsigned r = v.u + 0x7FFFu + ((v.u >> 16) & 1u);
    return (u16)(r >> 16);
}
__device__ __forceinline__ float bf2f(u16 h) {
    union { unsigned u; float f; } v; v.u = ((unsigned)h) << 16;
    return v.f;
}
__device__ __forceinline__ void split2(float f, u16& h, u16& l) {
    h = f2bf(f);
    l = f2bf(f - bf2f(h));
}

// ---------------- small kernels ----------------

__global__ void k_zero_int(int* __restrict__ p, int n) {
    int i = blockIdx.x * 256 + threadIdx.x;
    if (i < n) p[i] = 0;
}

__global__ void k_deg(const int* __restrict__ dst, int* __restrict__ deg, int E) {
    int e = blockIdx.x * 256 + threadIdx.x;
    if (e < E) atomicAdd(&deg[dst[e]], 1);
}

__global__ void k_dinv(const int* __restrict__ deg, float* __restrict__ dinv, int N) {
    int i = blockIdx.x * 256 + threadIdx.x;
    if (i < N) dinv[i] = rsqrtf((float)(deg[i] + 1));  // +1 self-loop
}

__global__ void k_count(const int* __restrict__ dst, int* __restrict__ ecnt, int E) {
    int e = blockIdx.x * 256 + threadIdx.x;
    if (e < E) atomicAdd(&ecnt[dst[e] / 30], 1);
}

__global__ __launch_bounds__(1024) void k_scan(const int* __restrict__ ecnt,
                                               int* __restrict__ estart,
                                               int* __restrict__ ecursor) {
    __shared__ int sh[1024];
    int t = threadIdx.x;
    int loc[8]; int sum = 0;
#pragma unroll
    for (int i = 0; i < 8; i++) { loc[i] = ecnt[t * 8 + i]; sum += loc[i]; }
    sh[t] = sum;
    __syncthreads();
    for (int off = 1; off < 1024; off <<= 1) {
        int v = (t >= off) ? sh[t - off] : 0;
        __syncthreads();
        sh[t] += v;
        __syncthreads();
    }
    int run = sh[t] - sum;
#pragma unroll
    for (int i = 0; i < 8; i++) {
        estart[t * 8 + i] = run;
        ecursor[t * 8 + i] = run;
        run += loc[i];
    }
}

__global__ void k_bucket(const int* __restrict__ ei, int* __restrict__ ecursor,
                         unsigned short* __restrict__ sE, int E) {
    int e = blockIdx.x * 256 + threadIdx.x;
    if (e >= E) return;
    int s = ei[e], d = ei[E + e];
    int g = d / 30;
    int p = atomicAdd(&ecursor[g], 1);
    sE[p] = (unsigned short)((s - g * 30) | ((d - g * 30) << 5));
}

// split fp32 W[K][F] -> transposed hi/lo bf16 [F][Kp], zero-padded K->Kp
__global__ void k_split_t(const float* __restrict__ W, u16* __restrict__ th,
                          u16* __restrict__ tl, int K, int F, int Kp) {
    int idx = blockIdx.x * 256 + threadIdx.x;
    if (idx >= F * Kp) return;
    int f = idx / Kp, k = idx % Kp;
    float v = (k < K) ? W[(size_t)k * F + f] : 0.f;
    u16 h, l; split2(v, h, l);
    th[idx] = h; tl[idx] = l;
}

// ---------------- per-graph LDS aggregation, hi/lo split output ----------------
// out row layout (packed, row-local, in-place safe): [hi x F][lo x F] u16
template<int F, int NG, bool EPI>
__global__ __launch_bounds__(256) void k_agg(const float* in, const float* __restrict__ dinv,
                                             const unsigned short* __restrict__ sE,
                                             const int* __restrict__ estart,
                                             const int* __restrict__ ecnt,
                                             const float* __restrict__ bias,
                                             u16* outp) {
    __shared__ float in_l[NG * 30 * F];
    __shared__ float out_l[NG * 30 * F];
    __shared__ float dv[NG * 30];
    int t = threadIdx.x;
    int g0 = blockIdx.x * NG;
    size_t base = (size_t)g0 * 30 * F;
    const int TOT4 = NG * 30 * F / 4;
    const float4* gin = (const float4*)(in + base);
    for (int i = t; i < TOT4; i += 256) ((float4*)in_l)[i] = gin[i];
    if (t < NG * 30) dv[t] = dinv[g0 * 30 + t];
    __syncthreads();

    int gi = t / F;
    int c = t % F;
#pragma unroll
    for (int i = 0; i < 30; i++) {
        float d = dv[gi * 30 + i];
        out_l[(gi * 30 + i) * F + c] = in_l[(gi * 30 + i) * F + c] * d * d;
    }
    int g = g0 + gi;
    int cnt = ecnt[g];
    int st = estart[g];
    for (int j = 0; j < cnt; j++) {
        int p = sE[st + j];
        int s = p & 31, d = p >> 5;
        float nm = dv[gi * 30 + s] * dv[gi * 30 + d];
        out_l[(gi * 30 + d) * F + c] += in_l[(gi * 30 + s) * F + c] * nm;
    }
    __syncthreads();

    u16* gout = outp + (size_t)g0 * 30 * 2 * F;
    for (int i = t; i < TOT4; i += 256) {
        float4 v = ((float4*)out_l)[i];
        int r = (i * 4) / F, cc = (i * 4) % F;
        if (EPI) {
            float4 bb = *(const float4*)(bias + cc);
            v.x = fmaxf(v.x + bb.x, 0.f);
            v.y = fmaxf(v.y + bb.y, 0.f);
            v.z = fmaxf(v.z + bb.z, 0.f);
            v.w = fmaxf(v.w + bb.w, 0.f);
        }
        ushort4 hv, lv;
        split2(v.x, hv.x, lv.x);
        split2(v.y, hv.y, lv.y);
        split2(v.z, hv.z, lv.z);
        split2(v.w, hv.w, lv.w);
        *(ushort4*)(gout + (size_t)r * 2 * F + cc) = hv;
        *(ushort4*)(gout + (size_t)r * 2 * F + F + cc) = lv;
    }
}

// ---------------- split-bf16 MFMA GEMM ----------------
// Y[N,F] = X[N,K] @ W[K,F]; 128 x (NT*32) tile, 4 waves 2x2, 16x16x32 bf16.
// XSPLIT: X is packed hi/lo u16 rows (2K shorts/row); else fp32, split in-kernel.
// EPI: 0 none, 1 bias+relu.
template<int NT, bool XSPLIT, int EPI>
__global__ __launch_bounds__(256) void k_mgemm(const float* __restrict__ Xf,
        const u16* __restrict__ Xs, const u16* __restrict__ Wth,
        const u16* __restrict__ Wtl, const float* __restrict__ bias,
        float* __restrict__ Y, int K, int Kp, int F) {
    const int BN = NT * 32;
    __shared__ __align__(16) u16 Xh_l[128 * 40];
    __shared__ __align__(16) u16 Xl_l[128 * 40];
    __shared__ __align__(16) u16 Wh_l[BN * 40];
    __shared__ __align__(16) u16 Wl_l[BN * 40];
    int t = threadIdx.x;
    int row0 = blockIdx.x * 128, col0 = blockIdx.y * BN;
    int wave = t >> 6, lane = t & 63, quad = lane >> 4, l15 = lane & 15;
    int wm = wave >> 1, wn = wave & 1;
    f32x4 acc[4][NT];
#pragma unroll
    for (int mi = 0; mi < 4; mi++)
#pragma unroll
        for (int ni = 0; ni < NT; ni++)
#pragma unroll
            for (int q = 0; q < 4; q++) acc[mi][ni][q] = 0.f;

    int nch = Kp >> 5;
    for (int ch = 0; ch < nch; ch++) {
        int kc = ch << 5;
        if (XSPLIT) {
#pragma unroll
            for (int i = 0; i < 4; i++) {
                int f4 = t + i * 256, r = f4 >> 3, c4 = f4 & 7;
                const u16* rp = Xs + (size_t)(row0 + r) * (2 * K) + kc + c4 * 4;
                *(ushort4*)&Xh_l[r * 40 + c4 * 4] = *(const ushort4*)rp;
                *(ushort4*)&Xl_l[r * 40 + c4 * 4] = *(const ushort4*)(rp + K);
            }
        } else {
#pragma unroll
            for (int i = 0; i < 16; i++) {
                int fl = t + i * 256, r = fl >> 5, kk = fl & 31;
                int k = kc + kk;
                float v = (k < K) ? Xf[(size_t)(row0 + r) * K + k] : 0.f;
                u16 h, l; split2(v, h, l);
                Xh_l[r * 40 + kk] = h; Xl_l[r * 40 + kk] = l;
            }
        }
#pragma unroll
        for (int i = 0; i < BN / 32; i++) {
            int f4 = t + i * 256, n = f4 >> 3, c4 = f4 & 7;
            size_t go = (size_t)(col0 + n) * Kp + kc + c4 * 4;
            *(ushort4*)&Wh_l[n * 40 + c4 * 4] = *(const ushort4*)(Wth + go);
            *(ushort4*)&Wl_l[n * 40 + c4 * 4] = *(const ushort4*)(Wtl + go);
        }
        __syncthreads();
        short8 ah[4], al[4], bh[NT], bl[NT];
#pragma unroll
        for (int mi = 0; mi < 4; mi++) {
            int r = wm * 64 + mi * 16 + l15;
            ah[mi] = *(const short8*)&Xh_l[r * 40 + quad * 8];
            al[mi] = *(const short8*)&Xl_l[r * 40 + quad * 8];
        }
#pragma unroll
        for (int ni = 0; ni < NT; ni++) {
            int c = wn * (BN / 2) + ni * 16 + l15;
            bh[ni] = *(const short8*)&Wh_l[c * 40 + quad * 8];
            bl[ni] = *(const short8*)&Wl_l[c * 40 + quad * 8];
        }
#pragma unroll
        for (int mi = 0; mi < 4; mi++)
#pragma unroll
            for (int ni = 0; ni < NT; ni++) {
                acc[mi][ni] = __builtin_amdgcn_mfma_f32_16x16x32_bf16(ah[mi], bh[ni], acc[mi][ni], 0, 0, 0);
                acc[mi][ni] = __builtin_amdgcn_mfma_f32_16x16x32_bf16(al[mi], bh[ni], acc[mi][ni], 0, 0, 0);
                acc[mi][ni] = __builtin_amdgcn_mfma_f32_16x16x32_bf16(ah[mi], bl[ni], acc[mi][ni], 0, 0, 0);
            }
        __syncthreads();
    }
#pragma unroll
    for (int mi = 0; mi < 4; mi++) {
        int row = row0 + wm * 64 + mi * 16 + quad * 4;
#pragma unroll
        for (int ni = 0; ni < NT; ni++) {
            int col = col0 + wn * (BN / 2) + ni * 16 + l15;
            float bv = (EPI == 1) ? bias[col] : 0.f;
#pragma unroll
            for (int rg = 0; rg < 4; rg++) {
                float v = acc[mi][ni][rg] + bv;
                if (EPI == 1) v = fmaxf(v, 0.f);
                Y[(size_t)(row + rg) * F + col] = v;
            }
        }
    }
}

// ---------------- layer-3 MFMA GEMM fused with mean pool ----------------
// block: 4 graphs (120 rows + 8 pad) x 128 cols; K=128. P[8192][256].
__global__ __launch_bounds__(256) void k_mgemm_pool(const u16* __restrict__ Xs,
        const u16* __restrict__ Wth, const u16* __restrict__ Wtl,
        const float* __restrict__ bias, float* __restrict__ P) {
    const int K = 128, Kp = 128;
    __shared__ __align__(16) u16 Xh_l[128 * 40];
    __shared__ __align__(16) u16 Xl_l[128 * 40];
    __shared__ __align__(16) u16 Wh_l[128 * 40];
    __shared__ __align__(16) u16 Wl_l[128 * 40];
    __shared__ float pooled_l[512];
    int t = threadIdx.x;
    int row0 = blockIdx.x * 120, col0 = blockIdx.y * 128;
    int wave = t >> 6, lane = t & 63, quad = lane >> 4, l15 = lane & 15;
    int wm = wave >> 1, wn = wave & 1;
    pooled_l[t] = 0.f; pooled_l[t + 256] = 0.f;
    f32x4 acc[4][4];
#pragma unroll
    for (int mi = 0; mi < 4; mi++)
#pragma unroll
        for (int ni = 0; ni < 4; ni++)
#pragma unroll
            for (int q = 0; q < 4; q++) acc[mi][ni][q] = 0.f;

    for (int ch = 0; ch < Kp / 32; ch++) {
        int kc = ch << 5;
#pragma unroll
        for (int i = 0; i < 4; i++) {
            int f4 = t + i * 256, r = f4 >> 3, c4 = f4 & 7;
            ushort4 h = {0, 0, 0, 0}, l = {0, 0, 0, 0};
            if (r < 120) {
                const u16* rp = Xs + (size_t)(row0 + r) * (2 * K) + kc + c4 * 4;
                h = *(const ushort4*)rp;
                l = *(const ushort4*)(rp + K);
            }
            *(ushort4*)&Xh_l[r * 40 + c4 * 4] = h;
            *(ushort4*)&Xl_l[r * 40 + c4 * 4] = l;
        }
#pragma unroll
        for (int i = 0; i < 4; i++) {
            int f4 = t + i * 256, n = f4 >> 3, c4 = f4 & 7;
            size_t go = (size_t)(col0 + n) * Kp + kc + c4 * 4;
            *(ushort4*)&Wh_l[n * 40 + c4 * 4] = *(const ushort4*)(Wth + go);
            *(ushort4*)&Wl_l[n * 40 + c4 * 4] = *(const ushort4*)(Wtl + go);
        }
        __syncthreads();
        short8 ah[4], al[4], bh[4], bl[4];
#pragma unroll
        for (int mi = 0; mi < 4; mi++) {
            int r = wm * 64 + mi * 16 + l15;
            ah[mi] = *(const short8*)&Xh_l[r * 40 + quad * 8];
            al[mi] = *(const short8*)&Xl_l[r * 40 + quad * 8];
        }
#pragma unroll
        for (int ni = 0; ni < 4; ni++) {
            int c = wn * 64 + ni * 16 + l15;
            bh[ni] = *(const short8*)&Wh_l[c * 40 + quad * 8];
            bl[ni] = *(const short8*)&Wl_l[c * 40 + quad * 8];
        }
#pragma unroll
        for (int mi = 0; mi < 4; mi++)
#pragma unroll
            for (int ni = 0; ni < 4; ni++) {
                acc[mi][ni] = __builtin_amdgcn_mfma_f32_16x16x32_bf16(ah[mi], bh[ni], acc[mi][ni], 0, 0, 0);
                acc[mi][ni] = __builtin_amdgcn_mfma_f32_16x16x32_bf16(al[mi], bh[ni], acc[mi][ni], 0, 0, 0);
                acc[mi][ni] = __builtin_amdgcn_mfma_f32_16x16x32_bf16(ah[mi], bl[ni], acc[mi][ni], 0, 0, 0);
            }
        __syncthreads();
    }
    // relu(acc + bias) -> per-graph LDS reduction
#pragma unroll
    for (int mi = 0; mi < 4; mi++) {
        int lr0 = wm * 64 + mi * 16 + quad * 4;
#pragma unroll
        for (int ni = 0; ni < 4; ni++) {
            int lc = wn * 64 + ni * 16 + l15;
            float bv = bias[col0 + lc];
#pragma unroll
            for (int rg = 0; rg < 4; rg++) {
                int lr = lr0 + rg;
                if (lr < 120) {
                    float v = fmaxf(acc[mi][ni][rg] + bv, 0.f);
                    atomicAdd(&pooled_l[(lr / 30) * 128 + lc], v);
                }
            }
        }
    }
    __syncthreads();
#pragma unroll
    for (int i = 0; i < 2; i++) {
        int idx = t + i * 256, g = idx >> 7, c = idx & 127;
        P[(size_t)(blockIdx.x * 4 + g) * 256 + col0 + c] = pooled_l[idx] * (1.f / 30.f);
    }
}

// ---------------- fp32 tiled GEMM (small tail GEMMs) ----------------
template<bool BIAS, bool RELU>
__global__ __launch_bounds__(256) void k_gemm(const float* __restrict__ X,
                                              const float* __restrict__ W,
                                              const float* __restrict__ bias,
                                              float* __restrict__ Y,
                                              int N, int K, int F) {
    __shared__ float Xs[64][33];
    __shared__ float Ws[32][65];
    int t = threadIdx.x;
    int row0 = blockIdx.x * 64;
    int col0 = blockIdx.y * 64;
    int tx = t & 15, ty = t >> 4;
    float acc[4][4] = {};
    for (int kc = 0; kc < K; kc += 32) {
#pragma unroll
        for (int i = 0; i < 8; i++) {
            int flat = t + i * 256;
            int r = flat >> 5, kk = flat & 31;
            int gr = row0 + r, gk = kc + kk;
            Xs[r][kk] = (gr < N && gk < K) ? X[(size_t)gr * K + gk] : 0.f;
        }
#pragma unroll
        for (int i = 0; i < 8; i++) {
            int flat = t + i * 256;
            int kk = flat >> 6, c = flat & 63;
            int gk = kc + kk, gc = col0 + c;
            Ws[kk][c] = (gk < K && gc < F) ? W[(size_t)gk * F + gc] : 0.f;
        }
        __syncthreads();
#pragma unroll
        for (int kk = 0; kk < 32; kk++) {
            float a[4], b[4];
#pragma unroll
            for (int i = 0; i < 4; i++) a[i] = Xs[ty * 4 + i][kk];
#pragma unroll
            for (int j = 0; j < 4; j++) b[j] = Ws[kk][tx * 4 + j];
#pragma unroll
            for (int i = 0; i < 4; i++)
#pragma unroll
                for (int j = 0; j < 4; j++)
                    acc[i][j] += a[i] * b[j];
        }
        __syncthreads();
    }
#pragma unroll
    for (int i = 0; i < 4; i++) {
        int gr = row0 + ty * 4 + i;
        if (gr >= N) continue;
#pragma unroll
        for (int j = 0; j < 4; j++) {
            int gc = col0 + tx * 4 + j;
            if (gc >= F) continue;
            float v = acc[i][j];
            if (BIAS) v += bias[gc];
            if (RELU) v = fmaxf(v, 0.f);
            Y[(size_t)gr * F + gc] = v;
        }
    }
}

// ---------------- combiner head ----------------
__global__ __launch_bounds__(64) void k_head(const float* __restrict__ drug,
                                             const float* __restrict__ cell,
                                             const float* __restrict__ Wm1, const float* __restrict__ bm1,
                                             const float* __restrict__ Wm2, const float* __restrict__ bm2,
                                             const float* __restrict__ Wo, const float* __restrict__ bo,
                                             float* __restrict__ out) {
    __shared__ float comb[128];
    __shared__ float z1[64];
    __shared__ float z2[32];
    int g = blockIdx.x, t = threadIdx.x;
    comb[t] = drug[(size_t)g * 64 + t];
    comb[64 + t] = cell[(size_t)g * 64 + t];
    __syncthreads();
    float s = bm1[t];
#pragma unroll 8
    for (int k = 0; k < 128; k++) s += comb[k] * Wm1[k * 64 + t];
    z1[t] = fmaxf(s, 0.f);
    __syncthreads();
    if (t < 32) {
        float s2 = bm2[t];
#pragma unroll 8
        for (int k = 0; k < 64; k++) s2 += z1[k] * Wm2[k * 32 + t];
        z2[t] = fmaxf(s2, 0.f);
    }
    __syncthreads();
    float v = (t < 32) ? z2[t] * Wo[t] : 0.f;
#pragma unroll
    for (int off = 32; off > 0; off >>= 1) v += __shfl_down(v, off);
    if (t == 0) out[g] = v + bo[0];
}

// ---------------- launch ----------------

extern "C" void kernel_launch(void* const* d_in, const int* in_sizes, int n_in,
                              void* d_out, int out_size, void* d_ws, size_t ws_size,
                              hipStream_t stream) {
    const float* x   = (const float*)d_in[0];
    const int*   ei  = (const int*)d_in[1];
    const float* cf  = (const float*)d_in[3];
    const float* W1  = (const float*)d_in[4];
    const float* b1  = (const float*)d_in[5];
    const float* W2  = (const float*)d_in[6];
    const float* b2  = (const float*)d_in[7];
    const float* W3  = (const float*)d_in[8];
    const float* b3  = (const float*)d_in[9];
    const float* Wd  = (const float*)d_in[10];
    const float* bd  = (const float*)d_in[11];
    const float* Wc1 = (const float*)d_in[12];
    const float* bc1 = (const float*)d_in[13];
    const float* Wc2 = (const float*)d_in[14];
    const float* bc2 = (const float*)d_in[15];
    const float* Wm1 = (const float*)d_in[16];
    const float* bm1 = (const float*)d_in[17];
    const float* Wm2 = (const float*)d_in[18];
    const float* bm2 = (const float*)d_in[19];
    const float* Wo  = (const float*)d_in[20];
    const float* bo  = (const float*)d_in[21];
    float* out = (float*)d_out;

    const int N = in_sizes[0] / 78;    // 245760
    const int E = in_sizes[1] / 2;     // 1,000,000
    const int B = in_sizes[3] / 1000;  // 8192

    char* w = (char*)d_ws;
    auto carve = [&](size_t bytes) { void* p = (void*)w; w += (bytes + 255) & ~(size_t)255; return p; };
    int*   deg    = (int*)  carve((size_t)N * 4);
    float* dinv   = (float*)carve((size_t)N * 4);
    int*   ecnt   = (int*)  carve((size_t)B * 4);
    int*   estart = (int*)  carve((size_t)B * 4);
    int*   ecur   = (int*)  carve((size_t)B * 4);
    unsigned short* sE = (unsigned short*)carve((size_t)E * 2);
    float* pooled = (float*)carve((size_t)B * 256 * 4);
    float* drug   = (float*)carve((size_t)B * 64 * 4);
    float* cell1  = (float*)carve((size_t)B * 128 * 4);
    float* cell2  = (float*)carve((size_t)B * 64 * 4);
    u16* W1th = (u16*)carve(64 * 96 * 2);     u16* W1tl = (u16*)carve(64 * 96 * 2);
    u16* W2th = (u16*)carve(128 * 64 * 2);    u16* W2tl = (u16*)carve(128 * 64 * 2);
    u16* W3th = (u16*)carve(256 * 128 * 2);   u16* W3tl = (u16*)carve(256 * 128 * 2);
    u16* Wc1th = (u16*)carve(128 * 1024 * 2); u16* Wc1tl = (u16*)carve(128 * 1024 * 2);
    float* bufA = (float*)carve((size_t)N * 64 * 4);   // t1 fp32, then h1 hi/lo packed (in-place)
    float* bufB = (float*)carve((size_t)N * 128 * 4);  // h2 fp32, then a3 hi/lo packed (in-place)

    auto g1 = [](int n) { return (n + 255) / 256; };

    // degrees, dinv, edge bucketing
    k_zero_int<<<g1(N), 256, 0, stream>>>(deg, N);
    k_zero_int<<<g1(B), 256, 0, stream>>>(ecnt, B);
    k_deg<<<g1(E), 256, 0, stream>>>(ei + E, deg, E);
    k_count<<<g1(E), 256, 0, stream>>>(ei + E, ecnt, E);
    k_dinv<<<g1(N), 256, 0, stream>>>(deg, dinv, N);
    k_scan<<<1, 1024, 0, stream>>>(ecnt, estart, ecur);
    k_bucket<<<g1(E), 256, 0, stream>>>(ei, ecur, sE, E);

    // weight pre-split (hi/lo bf16, transposed [F][Kp])
    k_split_t<<<g1(64 * 96), 256, 0, stream>>>(W1, W1th, W1tl, 78, 64, 96);
    k_split_t<<<g1(128 * 64), 256, 0, stream>>>(W2, W2th, W2tl, 64, 128, 64);
    k_split_t<<<g1(256 * 128), 256, 0, stream>>>(W3, W3th, W3tl, 128, 256, 128);
    k_split_t<<<g1(128 * 1024), 256, 0, stream>>>(Wc1, Wc1th, Wc1tl, 1000, 128, 1024);

    // layer 1: t1 = x@W1 (MFMA) ; h1 = relu(A@t1 + b1) -> hi/lo split
    k_mgemm<2, false, 0><<<dim3(N / 128, 1), 256, 0, stream>>>(x, nullptr, W1th, W1tl, nullptr, bufA, 78, 96, 64);
    k_agg<64, 4, true><<<B / 4, 256, 0, stream>>>(bufA, dinv, sE, estart, ecnt, b1, (u16*)bufA);

    // layer 2: h2 = relu((A@h1 ... wait) h1@W2 + b2) with h1 = split input
    k_mgemm<4, true, 1><<<dim3(N / 128, 1), 256, 0, stream>>>(nullptr, (u16*)bufA, W2th, W2tl, b2, bufB, 64, 64, 128);

    // a3 = A@h2 -> hi/lo split (in-place)
    k_agg<128, 2, false><<<B / 2, 256, 0, stream>>>(bufB, dinv, sE, estart, ecnt, nullptr, (u16*)bufB);

    // pooled = mean_graph relu(a3@W3 + b3)
    k_mgemm_pool<<<dim3(B / 4, 2), 256, 0, stream>>>((u16*)bufB, W3th, W3tl, b3, pooled);

    // drug = pooled @ Wd + bd
    k_gemm<true, false><<<dim3(B / 64, 1), 256, 0, stream>>>(pooled, Wd, bd, drug, B, 256, 64);

    // cell MLP
    k_mgemm<4, false, 1><<<dim3(B / 128, 1), 256, 0, stream>>>(cf, nullptr, Wc1th, Wc1tl, bc1, cell1, 1000, 1024, 128);
    k_gemm<true, false><<<dim3(B / 64, 1), 256, 0, stream>>>(cell1, Wc2, bc2, cell2, B, 128, 64);

    // combiner head
    k_head<<<B, 64, 0, stream>>>(drug, cell2, Wm1, bm1, Wm2, bm2, Wo, bo, out);
}

// Round 4
// 1084.517 us; speedup vs baseline: 4.3569x; 1.2673x over previous
//
#include <hip/hip_runtime.h>

typedef __attribute__((ext_vector_type(8))) short short8;
typedef __attribute__((ext_vector_type(4))) float f32x4;
typedef unsigned short u16;

__device__ __forceinline__ u16 f2bf(float f) {
    union { float f; unsigned u; } v; v.f = f;
    unsigned r = v.u + 0x7FFFu + ((v.u >> 16) & 1u);
    return (u16)(r >> 16);
}
__device__ __forceinline__ float bf2f(u16 h) {
    union { unsigned u; float f; } v; v.u = ((unsigned)h) << 16;
    return v.f;
}
__device__ __forceinline__ void split2(float f, u16& h, u16& l) {
    h = f2bf(f);
    l = f2bf(f - bf2f(h));
}

// ---------------- small kernels ----------------

__global__ void k_zero_int(int* __restrict__ p, int n) {
    int i = blockIdx.x * 256 + threadIdx.x;
    if (i < n) p[i] = 0;
}

__global__ void k_zero_f(float* __restrict__ p, int n) {
    int i = blockIdx.x * 256 + threadIdx.x;
    if (i < n) p[i] = 0.f;
}

__global__ void k_deg(const int* __restrict__ dst, int* __restrict__ deg, int E) {
    int e = blockIdx.x * 256 + threadIdx.x;
    if (e < E) atomicAdd(&deg[dst[e]], 1);
}

__global__ void k_dinv(const int* __restrict__ deg, float* __restrict__ dinv, int N) {
    int i = blockIdx.x * 256 + threadIdx.x;
    if (i < N) dinv[i] = rsqrtf((float)(deg[i] + 1));  // +1 self-loop
}

__global__ void k_count(const int* __restrict__ dst, int* __restrict__ ecnt, int E) {
    int e = blockIdx.x * 256 + threadIdx.x;
    if (e < E) atomicAdd(&ecnt[dst[e] / 30], 1);
}

__global__ __launch_bounds__(1024) void k_scan(const int* __restrict__ ecnt,
                                               int* __restrict__ estart,
                                               int* __restrict__ ecursor) {
    __shared__ int sh[1024];
    int t = threadIdx.x;
    int loc[8]; int sum = 0;
#pragma unroll
    for (int i = 0; i < 8; i++) { loc[i] = ecnt[t * 8 + i]; sum += loc[i]; }
    sh[t] = sum;
    __syncthreads();
    for (int off = 1; off < 1024; off <<= 1) {
        int v = (t >= off) ? sh[t - off] : 0;
        __syncthreads();
        sh[t] += v;
        __syncthreads();
    }
    int run = sh[t] - sum;
#pragma unroll
    for (int i = 0; i < 8; i++) {
        estart[t * 8 + i] = run;
        ecursor[t * 8 + i] = run;
        run += loc[i];
    }
}

__global__ void k_bucket(const int* __restrict__ ei, int* __restrict__ ecursor,
                         unsigned short* __restrict__ sE, int E) {
    int e = blockIdx.x * 256 + threadIdx.x;
    if (e >= E) return;
    int s = ei[e], d = ei[E + e];
    int g = d / 30;
    int p = atomicAdd(&ecursor[g], 1);
    sE[p] = (unsigned short)((s - g * 30) | ((d - g * 30) << 5));
}

// split fp32 W[K][F] -> transposed hi/lo bf16 [F][Kp], zero-padded K->Kp
__global__ void k_split_t(const float* __restrict__ W, u16* __restrict__ th,
                          u16* __restrict__ tl, int K, int F, int Kp) {
    int idx = blockIdx.x * 256 + threadIdx.x;
    if (idx >= F * Kp) return;
    int f = idx / Kp, k = idx % Kp;
    float v = (k < K) ? W[(size_t)k * F + f] : 0.f;
    u16 h, l; split2(v, h, l);
    th[idx] = h; tl[idx] = l;
}

// ---------------- fused layer-2: h2 = relu( relu(A@t1+b1) @ W2 + b2 ) ----------------
// block = 2 graphs (60 rows, M=64 padded), N=128, K=64. 512 threads = 8 waves (2x4).
__global__ __launch_bounds__(512) void k_l2(const float* __restrict__ t1,
        const float* __restrict__ dinv,
        const unsigned short* __restrict__ sE,
        const int* __restrict__ estart, const int* __restrict__ ecnt,
        const float* __restrict__ b1,
        const u16* __restrict__ Wth, const u16* __restrict__ Wtl,
        const float* __restrict__ b2, float* __restrict__ h2) {
    __shared__ float in_l[60 * 64];     // 15360 B
    __shared__ float h1_l[64 * 68];     // 17408 B (pad stride 68)
    __shared__ float dv[64];
    int t = threadIdx.x;
    int g0 = blockIdx.x * 2;
    // stage t1 tile (60x64)
    const float4* src = (const float4*)(t1 + (size_t)g0 * 30 * 64);
    for (int i = t; i < 960; i += 512) ((float4*)in_l)[i] = src[i];
    if (t < 60) dv[t] = dinv[g0 * 30 + t];
    if (t >= 256) {  // zero pad rows 60..63 (cols 0..63)
        int idx = t - 256, r = 60 + (idx >> 6), c = idx & 63;
        h1_l[r * 68 + c] = 0.f;
    }
    __syncthreads();
    if (t < 128) {
        int g = t >> 6, c = t & 63;
        for (int i = 0; i < 30; i++) {
            float d = dv[g * 30 + i];
            h1_l[(g * 30 + i) * 68 + c] = in_l[(g * 30 + i) * 64 + c] * d * d;
        }
        int gg = g0 + g;
        int cnt = ecnt[gg], st = estart[gg];
        for (int j = 0; j < cnt; j++) {
            int p = sE[st + j];
            int s = p & 31, d = p >> 5;
            h1_l[(g * 30 + d) * 68 + c] += in_l[(g * 30 + s) * 64 + c] * (dv[g * 30 + s] * dv[g * 30 + d]);
        }
        float bb = b1[c];
        for (int i = 0; i < 30; i++) {
            float v = h1_l[(g * 30 + i) * 68 + c];
            h1_l[(g * 30 + i) * 68 + c] = fmaxf(v + bb, 0.f);
        }
    }
    __syncthreads();
    // GEMM: M=64, N=128, K=64 (2 chunks of 32)
    int wave = t >> 6, lane = t & 63, quad = lane >> 4, l15 = lane & 15;
    int wm = wave >> 2, wn = wave & 3;
    f32x4 acc[2][2];
#pragma unroll
    for (int mi = 0; mi < 2; mi++)
#pragma unroll
        for (int ni = 0; ni < 2; ni++)
#pragma unroll
            for (int q = 0; q < 4; q++) acc[mi][ni][q] = 0.f;
#pragma unroll
    for (int ch = 0; ch < 2; ch++) {
        int kc = ch * 32;
        short8 ah[2], al[2], bh[2], bl[2];
#pragma unroll
        for (int mi = 0; mi < 2; mi++) {
            int r = wm * 32 + mi * 16 + l15;
            const float* ap = &h1_l[r * 68 + kc + quad * 8];
            f32x4 v0 = *(const f32x4*)ap;
            f32x4 v1 = *(const f32x4*)(ap + 4);
#pragma unroll
            for (int j = 0; j < 4; j++) {
                u16 h, l;
                split2(v0[j], h, l); ah[mi][j] = (short)h; al[mi][j] = (short)l;
                split2(v1[j], h, l); ah[mi][4 + j] = (short)h; al[mi][4 + j] = (short)l;
            }
        }
#pragma unroll
        for (int ni = 0; ni < 2; ni++) {
            int col = wn * 32 + ni * 16 + l15;
            size_t go = (size_t)col * 64 + kc + quad * 8;
            bh[ni] = *(const short8*)(Wth + go);
            bl[ni] = *(const short8*)(Wtl + go);
        }
#pragma unroll
        for (int mi = 0; mi < 2; mi++)
#pragma unroll
            for (int ni = 0; ni < 2; ni++) {
                acc[mi][ni] = __builtin_amdgcn_mfma_f32_16x16x32_bf16(ah[mi], bh[ni], acc[mi][ni], 0, 0, 0);
                acc[mi][ni] = __builtin_amdgcn_mfma_f32_16x16x32_bf16(al[mi], bh[ni], acc[mi][ni], 0, 0, 0);
                acc[mi][ni] = __builtin_amdgcn_mfma_f32_16x16x32_bf16(ah[mi], bl[ni], acc[mi][ni], 0, 0, 0);
            }
    }
    // epilogue: relu(acc + b2) -> h2 global (rows < 60)
    size_t rowbase = (size_t)g0 * 30;
#pragma unroll
    for (int ni = 0; ni < 2; ni++) {
        int col = wn * 32 + ni * 16 + l15;
        float bv = b2[col];
#pragma unroll
        for (int mi = 0; mi < 2; mi++) {
            int r0 = wm * 32 + mi * 16 + quad * 4;
#pragma unroll
            for (int rg = 0; rg < 4; rg++) {
                int r = r0 + rg;
                if (r < 60)
                    h2[(rowbase + r) * 128 + col] = fmaxf(acc[mi][ni][rg] + bv, 0.f);
            }
        }
    }
}

// ---------------- fused layer-3: P = mean_graph relu( (A@h2) @ W3 + b3 ) ----------------
// block = 2 graphs, M=64 (60+4 pad), N=256, K=128. 512 threads = 8 waves (2x4).
__global__ __launch_bounds__(512) void k_l3(const float* __restrict__ h2,
        const float* __restrict__ dinv,
        const unsigned short* __restrict__ sE,
        const int* __restrict__ estart, const int* __restrict__ ecnt,
        const u16* __restrict__ Wth, const u16* __restrict__ Wtl,
        const float* __restrict__ bias, float* __restrict__ P) {
    __shared__ float in_l[60 * 128];    // 30720 B
    __shared__ float a3[64 * 132];      // 33792 B (pad stride 132)
    __shared__ float dv[64];
    int t = threadIdx.x;
    int g0 = blockIdx.x * 2;
    const float4* src = (const float4*)(h2 + (size_t)g0 * 30 * 128);
    for (int i = t; i < 1920; i += 512) ((float4*)in_l)[i] = src[i];
    if (t < 60) dv[t] = dinv[g0 * 30 + t];
    {   // zero pad rows 60..63 (cols 0..127)
        int r = 60 + (t >> 7), c = t & 127;
        a3[r * 132 + c] = 0.f;
    }
    __syncthreads();
    if (t < 256) {
        int g = t >> 7, c = t & 127;
        for (int i = 0; i < 30; i++) {
            float d = dv[g * 30 + i];
            a3[(g * 30 + i) * 132 + c] = in_l[(g * 30 + i) * 128 + c] * d * d;
        }
        int gg = g0 + g;
        int cnt = ecnt[gg], st = estart[gg];
        for (int j = 0; j < cnt; j++) {
            int p = sE[st + j];
            int s = p & 31, d = p >> 5;
            a3[(g * 30 + d) * 132 + c] += in_l[(g * 30 + s) * 128 + c] * (dv[g * 30 + s] * dv[g * 30 + d]);
        }
    }
    __syncthreads();
    // GEMM: M=64, N=256, K=128 (4 chunks)
    int wave = t >> 6, lane = t & 63, quad = lane >> 4, l15 = lane & 15;
    int wm = wave >> 2, wn = wave & 3;
    f32x4 acc[2][4];
#pragma unroll
    for (int mi = 0; mi < 2; mi++)
#pragma unroll
        for (int ni = 0; ni < 4; ni++)
#pragma unroll
            for (int q = 0; q < 4; q++) acc[mi][ni][q] = 0.f;
#pragma unroll
    for (int ch = 0; ch < 4; ch++) {
        int kc = ch * 32;
        short8 ah[2], al[2], bh[4], bl[4];
#pragma unroll
        for (int ni = 0; ni < 4; ni++) {
            int col = wn * 64 + ni * 16 + l15;
            size_t go = (size_t)col * 128 + kc + quad * 8;
            bh[ni] = *(const short8*)(Wth + go);
            bl[ni] = *(const short8*)(Wtl + go);
        }
#pragma unroll
        for (int mi = 0; mi < 2; mi++) {
            int r = wm * 32 + mi * 16 + l15;
            const float* ap = &a3[r * 132 + kc + quad * 8];
            f32x4 v0 = *(const f32x4*)ap;
            f32x4 v1 = *(const f32x4*)(ap + 4);
#pragma unroll
            for (int j = 0; j < 4; j++) {
                u16 h, l;
                split2(v0[j], h, l); ah[mi][j] = (short)h; al[mi][j] = (short)l;
                split2(v1[j], h, l); ah[mi][4 + j] = (short)h; al[mi][4 + j] = (short)l;
            }
        }
#pragma unroll
        for (int mi = 0; mi < 2; mi++)
#pragma unroll
            for (int ni = 0; ni < 4; ni++) {
                acc[mi][ni] = __builtin_amdgcn_mfma_f32_16x16x32_bf16(ah[mi], bh[ni], acc[mi][ni], 0, 0, 0);
                acc[mi][ni] = __builtin_amdgcn_mfma_f32_16x16x32_bf16(al[mi], bh[ni], acc[mi][ni], 0, 0, 0);
                acc[mi][ni] = __builtin_amdgcn_mfma_f32_16x16x32_bf16(ah[mi], bl[ni], acc[mi][ni], 0, 0, 0);
            }
    }
    // epilogue: relu(acc+b3), in-register pool, write P (P pre-zeroed; g1 via atomics)
    const float sc = 1.0f / 30.0f;
#pragma unroll
    for (int ni = 0; ni < 4; ni++) {
        int col = wn * 64 + ni * 16 + l15;
        float bv = bias[col];
        float p0 = 0.f, p1 = 0.f;
#pragma unroll
        for (int mi = 0; mi < 2; mi++) {
            int r0 = wm * 32 + mi * 16 + quad * 4;
#pragma unroll
            for (int rg = 0; rg < 4; rg++) {
                int r = r0 + rg;
                if (r < 60) {
                    float v = fmaxf(acc[mi][ni][rg] + bv, 0.f);
                    if (r < 30) p0 += v; else p1 += v;
                }
            }
        }
        p0 += __shfl_down(p0, 32); p0 += __shfl_down(p0, 16);
        p1 += __shfl_down(p1, 32); p1 += __shfl_down(p1, 16);
        if (lane < 16) {
            if (wm == 0) {
                P[(size_t)g0 * 256 + col] = p0 * sc;  // rows 0..29 exclusive to wm0
                atomicAdd(&P[(size_t)(g0 + 1) * 256 + col], p1 * sc);  // rows 30,31
            } else {
                atomicAdd(&P[(size_t)(g0 + 1) * 256 + col], p1 * sc);  // rows 32..59
            }
        }
    }
}

// ---------------- split-bf16 MFMA GEMM (L1 and cell1) ----------------
template<int NT, bool XSPLIT, int EPI>
__global__ __launch_bounds__(256) void k_mgemm(const float* __restrict__ Xf,
        const u16* __restrict__ Xs, const u16* __restrict__ Wth,
        const u16* __restrict__ Wtl, const float* __restrict__ bias,
        float* __restrict__ Y, int K, int Kp, int F) {
    const int BN = NT * 32;
    __shared__ __align__(16) u16 Xh_l[128 * 40];
    __shared__ __align__(16) u16 Xl_l[128 * 40];
    __shared__ __align__(16) u16 Wh_l[BN * 40];
    __shared__ __align__(16) u16 Wl_l[BN * 40];
    int t = threadIdx.x;
    int row0 = blockIdx.x * 128, col0 = blockIdx.y * BN;
    int wave = t >> 6, lane = t & 63, quad = lane >> 4, l15 = lane & 15;
    int wm = wave >> 1, wn = wave & 1;
    f32x4 acc[4][NT];
#pragma unroll
    for (int mi = 0; mi < 4; mi++)
#pragma unroll
        for (int ni = 0; ni < NT; ni++)
#pragma unroll
            for (int q = 0; q < 4; q++) acc[mi][ni][q] = 0.f;

    int nch = Kp >> 5;
    for (int ch = 0; ch < nch; ch++) {
        int kc = ch << 5;
        if (XSPLIT) {
#pragma unroll
            for (int i = 0; i < 4; i++) {
                int f4 = t + i * 256, r = f4 >> 3, c4 = f4 & 7;
                const u16* rp = Xs + (size_t)(row0 + r) * (2 * K) + kc + c4 * 4;
                *(ushort4*)&Xh_l[r * 40 + c4 * 4] = *(const ushort4*)rp;
                *(ushort4*)&Xl_l[r * 40 + c4 * 4] = *(const ushort4*)(rp + K);
            }
        } else {
#pragma unroll
            for (int i = 0; i < 16; i++) {
                int fl = t + i * 256, r = fl >> 5, kk = fl & 31;
                int k = kc + kk;
                float v = (k < K) ? Xf[(size_t)(row0 + r) * K + k] : 0.f;
                u16 h, l; split2(v, h, l);
                Xh_l[r * 40 + kk] = h; Xl_l[r * 40 + kk] = l;
            }
        }
#pragma unroll
        for (int i = 0; i < BN / 32; i++) {
            int f4 = t + i * 256, n = f4 >> 3, c4 = f4 & 7;
            size_t go = (size_t)(col0 + n) * Kp + kc + c4 * 4;
            *(ushort4*)&Wh_l[n * 40 + c4 * 4] = *(const ushort4*)(Wth + go);
            *(ushort4*)&Wl_l[n * 40 + c4 * 4] = *(const ushort4*)(Wtl + go);
        }
        __syncthreads();
        short8 ah[4], al[4], bh[NT], bl[NT];
#pragma unroll
        for (int mi = 0; mi < 4; mi++) {
            int r = wm * 64 + mi * 16 + l15;
            ah[mi] = *(const short8*)&Xh_l[r * 40 + quad * 8];
            al[mi] = *(const short8*)&Xl_l[r * 40 + quad * 8];
        }
#pragma unroll
        for (int ni = 0; ni < NT; ni++) {
            int c = wn * (BN / 2) + ni * 16 + l15;
            bh[ni] = *(const short8*)&Wh_l[c * 40 + quad * 8];
            bl[ni] = *(const short8*)&Wl_l[c * 40 + quad * 8];
        }
#pragma unroll
        for (int mi = 0; mi < 4; mi++)
#pragma unroll
            for (int ni = 0; ni < NT; ni++) {
                acc[mi][ni] = __builtin_amdgcn_mfma_f32_16x16x32_bf16(ah[mi], bh[ni], acc[mi][ni], 0, 0, 0);
                acc[mi][ni] = __builtin_amdgcn_mfma_f32_16x16x32_bf16(al[mi], bh[ni], acc[mi][ni], 0, 0, 0);
                acc[mi][ni] = __builtin_amdgcn_mfma_f32_16x16x32_bf16(ah[mi], bl[ni], acc[mi][ni], 0, 0, 0);
            }
        __syncthreads();
    }
#pragma unroll
    for (int mi = 0; mi < 4; mi++) {
        int row = row0 + wm * 64 + mi * 16 + quad * 4;
#pragma unroll
        for (int ni = 0; ni < NT; ni++) {
            int col = col0 + wn * (BN / 2) + ni * 16 + l15;
            float bv = (EPI == 1) ? bias[col] : 0.f;
#pragma unroll
            for (int rg = 0; rg < 4; rg++) {
                float v = acc[mi][ni][rg] + bv;
                if (EPI == 1) v = fmaxf(v, 0.f);
                Y[(size_t)(row + rg) * F + col] = v;
            }
        }
    }
}

// ---------------- fp32 tiled GEMM (small tail GEMMs) ----------------
template<bool BIAS, bool RELU>
__global__ __launch_bounds__(256) void k_gemm(const float* __restrict__ X,
                                              const float* __restrict__ W,
                                              const float* __restrict__ bias,
                                              float* __restrict__ Y,
                                              int N, int K, int F) {
    __shared__ float Xs[64][33];
    __shared__ float Ws[32][65];
    int t = threadIdx.x;
    int row0 = blockIdx.x * 64;
    int col0 = blockIdx.y * 64;
    int tx = t & 15, ty = t >> 4;
    float acc[4][4] = {};
    for (int kc = 0; kc < K; kc += 32) {
#pragma unroll
        for (int i = 0; i < 8; i++) {
            int flat = t + i * 256;
            int r = flat >> 5, kk = flat & 31;
            int gr = row0 + r, gk = kc + kk;
            Xs[r][kk] = (gr < N && gk < K) ? X[(size_t)gr * K + gk] : 0.f;
        }
#pragma unroll
        for (int i = 0; i < 8; i++) {
            int flat = t + i * 256;
            int kk = flat >> 6, c = flat & 63;
            int gk = kc + kk, gc = col0 + c;
            Ws[kk][c] = (gk < K && gc < F) ? W[(size_t)gk * F + gc] : 0.f;
        }
        __syncthreads();
#pragma unroll
        for (int kk = 0; kk < 32; kk++) {
            float a[4], b[4];
#pragma unroll
            for (int i = 0; i < 4; i++) a[i] = Xs[ty * 4 + i][kk];
#pragma unroll
            for (int j = 0; j < 4; j++) b[j] = Ws[kk][tx * 4 + j];
#pragma unroll
            for (int i = 0; i < 4; i++)
#pragma unroll
                for (int j = 0; j < 4; j++)
                    acc[i][j] += a[i] * b[j];
        }
        __syncthreads();
    }
#pragma unroll
    for (int i = 0; i < 4; i++) {
        int gr = row0 + ty * 4 + i;
        if (gr >= N) continue;
#pragma unroll
        for (int j = 0; j < 4; j++) {
            int gc = col0 + tx * 4 + j;
            if (gc >= F) continue;
            float v = acc[i][j];
            if (BIAS) v += bias[gc];
            if (RELU) v = fmaxf(v, 0.f);
            Y[(size_t)gr * F + gc] = v;
        }
    }
}

// ---------------- combiner head ----------------
__global__ __launch_bounds__(64) void k_head(const float* __restrict__ drug,
                                             const float* __restrict__ cell,
                                             const float* __restrict__ Wm1, const float* __restrict__ bm1,
                                             const float* __restrict__ Wm2, const float* __restrict__ bm2,
                                             const float* __restrict__ Wo, const float* __restrict__ bo,
                                             float* __restrict__ out) {
    __shared__ float comb[128];
    __shared__ float z1[64];
    __shared__ float z2[32];
    int g = blockIdx.x, t = threadIdx.x;
    comb[t] = drug[(size_t)g * 64 + t];
    comb[64 + t] = cell[(size_t)g * 64 + t];
    __syncthreads();
    float s = bm1[t];
#pragma unroll 8
    for (int k = 0; k < 128; k++) s += comb[k] * Wm1[k * 64 + t];
    z1[t] = fmaxf(s, 0.f);
    __syncthreads();
    if (t < 32) {
        float s2 = bm2[t];
#pragma unroll 8
        for (int k = 0; k < 64; k++) s2 += z1[k] * Wm2[k * 32 + t];
        z2[t] = fmaxf(s2, 0.f);
    }
    __syncthreads();
    float v = (t < 32) ? z2[t] * Wo[t] : 0.f;
#pragma unroll
    for (int off = 32; off > 0; off >>= 1) v += __shfl_down(v, off);
    if (t == 0) out[g] = v + bo[0];
}

// ---------------- launch ----------------

extern "C" void kernel_launch(void* const* d_in, const int* in_sizes, int n_in,
                              void* d_out, int out_size, void* d_ws, size_t ws_size,
                              hipStream_t stream) {
    const float* x   = (const float*)d_in[0];
    const int*   ei  = (const int*)d_in[1];
    const float* cf  = (const float*)d_in[3];
    const float* W1  = (const float*)d_in[4];
    const float* b1  = (const float*)d_in[5];
    const float* W2  = (const float*)d_in[6];
    const float* b2  = (const float*)d_in[7];
    const float* W3  = (const float*)d_in[8];
    const float* b3  = (const float*)d_in[9];
    const float* Wd  = (const float*)d_in[10];
    const float* bd  = (const float*)d_in[11];
    const float* Wc1 = (const float*)d_in[12];
    const float* bc1 = (const float*)d_in[13];
    const float* Wc2 = (const float*)d_in[14];
    const float* bc2 = (const float*)d_in[15];
    const float* Wm1 = (const float*)d_in[16];
    const float* bm1 = (const float*)d_in[17];
    const float* Wm2 = (const float*)d_in[18];
    const float* bm2 = (const float*)d_in[19];
    const float* Wo  = (const float*)d_in[20];
    const float* bo  = (const float*)d_in[21];
    float* out = (float*)d_out;

    const int N = in_sizes[0] / 78;    // 245760
    const int E = in_sizes[1] / 2;     // 1,000,000
    const int B = in_sizes[3] / 1000;  // 8192

    char* w = (char*)d_ws;
    auto carve = [&](size_t bytes) { void* p = (void*)w; w += (bytes + 255) & ~(size_t)255; return p; };
    int*   deg    = (int*)  carve((size_t)N * 4);
    float* dinv   = (float*)carve((size_t)N * 4);
    int*   ecnt   = (int*)  carve((size_t)B * 4);
    int*   estart = (int*)  carve((size_t)B * 4);
    int*   ecur   = (int*)  carve((size_t)B * 4);
    unsigned short* sE = (unsigned short*)carve((size_t)E * 2);
    float* pooled = (float*)carve((size_t)B * 256 * 4);
    float* drug   = (float*)carve((size_t)B * 64 * 4);
    float* cell1  = (float*)carve((size_t)B * 128 * 4);
    float* cell2  = (float*)carve((size_t)B * 64 * 4);
    u16* W1th = (u16*)carve(64 * 96 * 2);     u16* W1tl = (u16*)carve(64 * 96 * 2);
    u16* W2th = (u16*)carve(128 * 64 * 2);    u16* W2tl = (u16*)carve(128 * 64 * 2);
    u16* W3th = (u16*)carve(256 * 128 * 2);   u16* W3tl = (u16*)carve(256 * 128 * 2);
    u16* Wc1th = (u16*)carve(128 * 1024 * 2); u16* Wc1tl = (u16*)carve(128 * 1024 * 2);
    float* bufA = (float*)carve((size_t)N * 64 * 4);   // t1 fp32
    float* bufB = (float*)carve((size_t)N * 128 * 4);  // h2 fp32

    auto g1 = [](int n) { return (n + 255) / 256; };

    // degrees, dinv, edge bucketing
    k_zero_int<<<g1(N), 256, 0, stream>>>(deg, N);
    k_zero_int<<<g1(B), 256, 0, stream>>>(ecnt, B);
    k_deg<<<g1(E), 256, 0, stream>>>(ei + E, deg, E);
    k_count<<<g1(E), 256, 0, stream>>>(ei + E, ecnt, E);
    k_dinv<<<g1(N), 256, 0, stream>>>(deg, dinv, N);
    k_scan<<<1, 1024, 0, stream>>>(ecnt, estart, ecur);
    k_bucket<<<g1(E), 256, 0, stream>>>(ei, ecur, sE, E);

    // weight pre-split (hi/lo bf16, transposed [F][Kp])
    k_split_t<<<g1(64 * 96), 256, 0, stream>>>(W1, W1th, W1tl, 78, 64, 96);
    k_split_t<<<g1(128 * 64), 256, 0, stream>>>(W2, W2th, W2tl, 64, 128, 64);
    k_split_t<<<g1(256 * 128), 256, 0, stream>>>(W3, W3th, W3tl, 128, 256, 128);
    k_split_t<<<g1(128 * 1024), 256, 0, stream>>>(Wc1, Wc1th, Wc1tl, 1000, 128, 1024);

    // zero pooled (k_l3 accumulates with atomics for g1 rows)
    k_zero_f<<<g1(B * 256), 256, 0, stream>>>(pooled, B * 256);

    // layer 1: t1 = x@W1 (MFMA)
    k_mgemm<2, false, 0><<<dim3(N / 128, 1), 256, 0, stream>>>(x, nullptr, W1th, W1tl, nullptr, bufA, 78, 96, 64);

    // fused layer 2: h2 = relu(relu(A@t1+b1)@W2 + b2)
    k_l2<<<B / 2, 512, 0, stream>>>(bufA, dinv, sE, estart, ecnt, b1, W2th, W2tl, b2, bufB);

    // fused layer 3: pooled = mean_graph relu((A@h2)@W3 + b3)
    k_l3<<<B / 2, 512, 0, stream>>>(bufB, dinv, sE, estart, ecnt, W3th, W3tl, b3, pooled);

    // drug = pooled @ Wd + bd
    k_gemm<true, false><<<dim3(B / 64, 1), 256, 0, stream>>>(pooled, Wd, bd, drug, B, 256, 64);

    // cell MLP
    k_mgemm<4, false, 1><<<dim3(B / 128, 1), 256, 0, stream>>>(cf, nullptr, Wc1th, Wc1tl, bc1, cell1, 1000, 1024, 128);
    k_gemm<true, false><<<dim3(B / 64, 1), 256, 0, stream>>>(cell1, Wc2, bc2, cell2, B, 128, 64);

    // combiner head
    k_head<<<B, 64, 0, stream>>>(drug, cell2, Wm1, bm1, Wm2, bm2, Wo, bo, out);
}

// Round 5
// 705.541 us; speedup vs baseline: 6.6971x; 1.5371x over previous
//
#include <hip/hip_runtime.h>

typedef __attribute__((ext_vector_type(8))) short short8;
typedef __attribute__((ext_vector_type(4))) short short4v;
typedef __attribute__((ext_vector_type(4))) float f32x4;
typedef unsigned short u16;

__device__ __forceinline__ u16 f2bf(float f) {
    union { float f; unsigned u; } v; v.f = f;
    unsigned r = v.u + 0x7FFFu + ((v.u >> 16) & 1u);
    return (u16)(r >> 16);
}
__device__ __forceinline__ float bf2f(u16 h) {
    union { unsigned u; float f; } v; v.u = ((unsigned)h) << 16;
    return v.f;
}
__device__ __forceinline__ void split2(float f, u16& h, u16& l) {
    h = f2bf(f);
    l = f2bf(f - bf2f(h));
}
// 8-byte-aligned LDS frag load (stride may not be 16B-aligned)
__device__ __forceinline__ short8 ld8(const u16* p) {
    short4v a = *(const short4v*)p;
    short4v b = *(const short4v*)(p + 4);
    short8 r;
    r[0] = a[0]; r[1] = a[1]; r[2] = a[2]; r[3] = a[3];
    r[4] = b[0]; r[5] = b[1]; r[6] = b[2]; r[7] = b[3];
    return r;
}
#define MFMA(A, B, C) __builtin_amdgcn_mfma_f32_16x16x32_bf16(A, B, C, 0, 0, 0)

// ---------------- prep kernels ----------------

__global__ void k_zero_int(int* __restrict__ p, int n) {
    int i = blockIdx.x * 256 + threadIdx.x;
    if (i < n) p[i] = 0;
}

__global__ void k_deg(const int* __restrict__ dst, int* __restrict__ deg, int E) {
    int e = blockIdx.x * 256 + threadIdx.x;
    if (e < E) atomicAdd(&deg[dst[e]], 1);
}

// per-graph edge counts from deg sums, then exclusive scan (B=8192, 1 block)
__global__ __launch_bounds__(1024) void k_scan(const int* __restrict__ deg,
                                               int* __restrict__ ecnt,
                                               int* __restrict__ estart,
                                               int* __restrict__ ecursor) {
    __shared__ int sh[1024];
    int t = threadIdx.x;
    int loc[8]; int sum = 0;
#pragma unroll
    for (int i = 0; i < 8; i++) {
        int g = t * 8 + i;
        int s = 0;
        for (int j = 0; j < 30; j++) s += deg[g * 30 + j];
        loc[i] = s; sum += s;
    }
    sh[t] = sum;
    __syncthreads();
    for (int off = 1; off < 1024; off <<= 1) {
        int v = (t >= off) ? sh[t - off] : 0;
        __syncthreads();
        sh[t] += v;
        __syncthreads();
    }
    int run = sh[t] - sum;
#pragma unroll
    for (int i = 0; i < 8; i++) {
        int g = t * 8 + i;
        ecnt[g] = loc[i];
        estart[g] = run;
        ecursor[g] = run;
        run += loc[i];
    }
}

__global__ void k_bucket(const int* __restrict__ ei, int* __restrict__ ecursor,
                         unsigned short* __restrict__ sE, int E) {
    int e = blockIdx.x * 256 + threadIdx.x;
    if (e >= E) return;
    int s = ei[e], d = ei[E + e];
    int g = d / 30;
    int p = atomicAdd(&ecursor[g], 1);
    sE[p] = (unsigned short)((s - g * 30) | ((d - g * 30) << 5));
}

// split fp32 W[K][F] -> transposed hi/lo bf16 [F][Kp], zero-padded K->Kp
__global__ void k_split_t(const float* __restrict__ W, u16* __restrict__ th,
                          u16* __restrict__ tl, int K, int F, int Kp) {
    int idx = blockIdx.x * 256 + threadIdx.x;
    if (idx >= F * Kp) return;
    int f = idx / Kp, k = idx % Kp;
    float v = (k < K) ? W[(size_t)k * F + f] : 0.f;
    u16 h, l; split2(v, h, l);
    th[idx] = h; tl[idx] = l;
}

// split cf rows: [B][1000] fp32 -> [B][2048] u16 (hi 0..1023 | lo 1024..2047)
__global__ void k_split_rows(const float* __restrict__ cf, u16* __restrict__ o, int B) {
    int idx = blockIdx.x * 256 + threadIdx.x;
    if (idx >= B * 1024) return;
    int r = idx >> 10, c = idx & 1023;
    float v = (c < 1000) ? cf[(size_t)r * 1000 + c] : 0.f;
    u16 h, l; split2(v, h, l);
    o[(size_t)r * 2048 + c] = h;
    o[(size_t)r * 2048 + 1024 + c] = l;
}

// ---------------- fused node pipeline: one block per graph ----------------
// x(30x78) -> GEMM1(W1,K96) -> t1 -> aggMFMA -> +b1,relu -> h1 -> GEMM2(W2,K64)
// -> +b2,relu -> h2 -> aggMFMA -> a3 -> GEMM3(W3,K128) -> +b3,relu -> mean pool
__global__ __launch_bounds__(512) void k_node(
    const float* __restrict__ x, const int* __restrict__ deg,
    const unsigned short* __restrict__ sE,
    const int* __restrict__ estart, const int* __restrict__ ecnt,
    const u16* __restrict__ W1h, const u16* __restrict__ W1l,
    const u16* __restrict__ W2h, const u16* __restrict__ W2l,
    const u16* __restrict__ W3h, const u16* __restrict__ W3l,
    const float* __restrict__ b1, const float* __restrict__ b2,
    const float* __restrict__ b3, float* __restrict__ P) {
    __shared__ __align__(16) char smem[47872];
    // phase-overlaid regions (u16 strides chosen for 8B alignment + bank spread)
    u16* xh  = (u16*)(smem + 0);        // [32][100]  P0-P4
    u16* xl  = (u16*)(smem + 6400);
    u16* h1h = (u16*)(smem + 0);        // [32][68]   P5-P6 (overlays x)
    u16* h1l = (u16*)(smem + 4352);
    u16* a3h = (u16*)(smem + 0);        // [32][132]  P7-P8 (overlays x/h1/t1T)
    u16* a3l = (u16*)(smem + 8448);
    u16* t1h = (u16*)(smem + 12800);    // [64][36]   P4-P5
    u16* t1l = (u16*)(smem + 17408);
    float* Afp = (float*)(smem + 22016); // [32][32]  P0-P2 (overlays h2T)
    u16* h2h = (u16*)(smem + 22016);    // [128][36]  P6-P7
    u16* h2l = (u16*)(smem + 31232);
    u16* Ah  = (u16*)(smem + 40448);    // [32][36]   P2-P7
    u16* Al  = (u16*)(smem + 42752);
    float* pool_l = (float*)(smem + 45056); // [256]  P2-P9
    float* dv     = (float*)(smem + 45056); // [32]   P0-P1 (dead before pool init)
    float* bias_l = (float*)(smem + 46080); // b1[64] b2[128] b3[256]

    int t = threadIdx.x;
    int g = blockIdx.x;

    // P0a: zero x region + Afp; dv; biases
    {
        uint* zp = (uint*)smem;
        for (int i = t; i < 3200; i += 512) zp[i] = 0;          // xh+xl
        uint* za = (uint*)Afp;
        for (int i = t; i < 1024; i += 512) za[i] = 0;          // Afp
        if (t < 32) dv[t] = (t < 30) ? rsqrtf((float)(deg[g * 30 + t] + 1)) : 0.f;
        if (t < 448) bias_l[t] = (t < 64) ? b1[t] : (t < 192 ? b2[t - 64] : b3[t - 192]);
    }
    __syncthreads();
    // P0b: stage x (2340 contiguous floats) split -> xh/xl; A diagonal
    {
        const float4* xg = (const float4*)(x + (size_t)g * 30 * 78);
        for (int i = t; i < 585; i += 512) {
            float4 v = xg[i];
            int base = i * 4;
            float vv[4] = {v.x, v.y, v.z, v.w};
#pragma unroll
            for (int j = 0; j < 4; j++) {
                int idx = base + j;
                int r = idx / 78, c = idx - r * 78;
                u16 h, l; split2(vv[j], h, l);
                xh[r * 100 + c] = h; xl[r * 100 + c] = l;
            }
        }
        if (t < 30) Afp[t * 32 + t] = dv[t] * dv[t];
    }
    __syncthreads();
    // P1: edge scatter into A (LDS atomics; handles duplicate/self edges)
    {
        int cnt = ecnt[g], st = estart[g];
        for (int j = t; j < cnt; j += 512) {
            int p = sE[st + j];
            int s = p & 31, d = p >> 5;
            atomicAdd(&Afp[d * 32 + s], dv[s] * dv[d]);
        }
    }
    __syncthreads();
    // P2: split A -> hi/lo; init pool accumulator (clobbers dv — dead)
    {
        for (int i = t; i < 1024; i += 512) {
            int r = i >> 5, c = i & 31;
            u16 h, l; split2(Afp[i], h, l);
            Ah[r * 36 + c] = h; Al[r * 36 + c] = l;
        }
        if (t < 256) pool_l[t] = 0.f;
    }
    __syncthreads();

    int wave = t >> 6, lane = t & 63, quad = lane >> 4, l15 = lane & 15;
    int wm = wave >> 2, wn = wave & 3;
    int arow = wm * 16 + l15;      // A-operand row (M=32)

    // P4: GEMM1  t1 = x @ W1   (M=32, N=64, K=96)
    {
        f32x4 acc = {0.f, 0.f, 0.f, 0.f};
        int col = wn * 16 + l15;
#pragma unroll
        for (int ch = 0; ch < 3; ch++) {
            int kc = ch * 32;
            short8 ah = ld8(&xh[arow * 100 + kc + quad * 8]);
            short8 al = ld8(&xl[arow * 100 + kc + quad * 8]);
            short8 bh = *(const short8*)(W1h + col * 96 + kc + quad * 8);
            short8 bl = *(const short8*)(W1l + col * 96 + kc + quad * 8);
            acc = MFMA(ah, bh, acc);
            acc = MFMA(al, bh, acc);
            acc = MFMA(ah, bl, acc);
        }
        // epi: write transposed t1T[col][row] (B-operand of agg1)
#pragma unroll
        for (int rg = 0; rg < 4; rg++) {
            int row = wm * 16 + quad * 4 + rg;
            u16 h, l; split2(acc[rg], h, l);
            t1h[col * 36 + row] = h;
            t1l[col * 36 + row] = l;
        }
    }
    __syncthreads();
    // P5: agg1  h1 = relu(A @ t1 + b1)   (M=32, N=64, K=32)
    {
        f32x4 acc = {0.f, 0.f, 0.f, 0.f};
        int col = wn * 16 + l15;
        short8 aAh = ld8(&Ah[arow * 36 + quad * 8]);
        short8 aAl = ld8(&Al[arow * 36 + quad * 8]);
        short8 bh = ld8(&t1h[col * 36 + quad * 8]);
        short8 bl = ld8(&t1l[col * 36 + quad * 8]);
        acc = MFMA(aAh, bh, acc);
        acc = MFMA(aAl, bh, acc);
        acc = MFMA(aAh, bl, acc);
        float bb = bias_l[col];
#pragma unroll
        for (int rg = 0; rg < 4; rg++) {
            int row = wm * 16 + quad * 4 + rg;
            float v = fmaxf(acc[rg] + bb, 0.f);
            u16 h, l; split2(v, h, l);
            h1h[row * 68 + col] = h;
            h1l[row * 68 + col] = l;
        }
    }
    __syncthreads();
    // P6: GEMM2  h2 = relu(h1 @ W2 + b2)  (M=32, N=128, K=64)
    {
        f32x4 acc[2] = {{0.f,0.f,0.f,0.f},{0.f,0.f,0.f,0.f}};
#pragma unroll
        for (int ch = 0; ch < 2; ch++) {
            int kc = ch * 32;
            short8 ah = ld8(&h1h[arow * 68 + kc + quad * 8]);
            short8 al = ld8(&h1l[arow * 68 + kc + quad * 8]);
#pragma unroll
            for (int ni = 0; ni < 2; ni++) {
                int col = wn * 32 + ni * 16 + l15;
                short8 bh = *(const short8*)(W2h + col * 64 + kc + quad * 8);
                short8 bl = *(const short8*)(W2l + col * 64 + kc + quad * 8);
                acc[ni] = MFMA(ah, bh, acc[ni]);
                acc[ni] = MFMA(al, bh, acc[ni]);
                acc[ni] = MFMA(ah, bl, acc[ni]);
            }
        }
#pragma unroll
        for (int ni = 0; ni < 2; ni++) {
            int col = wn * 32 + ni * 16 + l15;
            float bb = bias_l[64 + col];
#pragma unroll
            for (int rg = 0; rg < 4; rg++) {
                int row = wm * 16 + quad * 4 + rg;
                float v = fmaxf(acc[ni][rg] + bb, 0.f);
                u16 h, l; split2(v, h, l);
                h2h[col * 36 + row] = h;   // transposed: B-operand of agg2
                h2l[col * 36 + row] = l;
            }
        }
    }
    __syncthreads();
    // P7: agg2  a3 = A @ h2   (M=32, N=128, K=32)
    {
        f32x4 acc[2] = {{0.f,0.f,0.f,0.f},{0.f,0.f,0.f,0.f}};
        short8 aAh = ld8(&Ah[arow * 36 + quad * 8]);
        short8 aAl = ld8(&Al[arow * 36 + quad * 8]);
#pragma unroll
        for (int ni = 0; ni < 2; ni++) {
            int col = wn * 32 + ni * 16 + l15;
            short8 bh = ld8(&h2h[col * 36 + quad * 8]);
            short8 bl = ld8(&h2l[col * 36 + quad * 8]);
            acc[ni] = MFMA(aAh, bh, acc[ni]);
            acc[ni] = MFMA(aAl, bh, acc[ni]);
            acc[ni] = MFMA(aAh, bl, acc[ni]);
        }
#pragma unroll
        for (int ni = 0; ni < 2; ni++) {
            int col = wn * 32 + ni * 16 + l15;
#pragma unroll
            for (int rg = 0; rg < 4; rg++) {
                int row = wm * 16 + quad * 4 + rg;
                u16 h, l; split2(acc[ni][rg], h, l);
                a3h[row * 132 + col] = h;
                a3l[row * 132 + col] = l;
            }
        }
    }
    __syncthreads();
    // P8: GEMM3 + pool  (M=32, N=256, K=128)
    {
        f32x4 acc[4] = {{0.f,0.f,0.f,0.f},{0.f,0.f,0.f,0.f},{0.f,0.f,0.f,0.f},{0.f,0.f,0.f,0.f}};
#pragma unroll
        for (int ch = 0; ch < 4; ch++) {
            int kc = ch * 32;
            short8 ah = ld8(&a3h[arow * 132 + kc + quad * 8]);
            short8 al = ld8(&a3l[arow * 132 + kc + quad * 8]);
#pragma unroll
            for (int ni = 0; ni < 4; ni++) {
                int col = wn * 64 + ni * 16 + l15;
                short8 bh = *(const short8*)(W3h + col * 128 + kc + quad * 8);
                short8 bl = *(const short8*)(W3l + col * 128 + kc + quad * 8);
                acc[ni] = MFMA(ah, bh, acc[ni]);
                acc[ni] = MFMA(al, bh, acc[ni]);
                acc[ni] = MFMA(ah, bl, acc[ni]);
            }
        }
#pragma unroll
        for (int ni = 0; ni < 4; ni++) {
            int col = wn * 64 + ni * 16 + l15;
            float bb = bias_l[192 + col];
            float p = 0.f;
#pragma unroll
            for (int rg = 0; rg < 4; rg++) {
                int row = wm * 16 + quad * 4 + rg;
                if (row < 30) p += fmaxf(acc[ni][rg] + bb, 0.f);
            }
            p += __shfl_down(p, 32);
            p += __shfl_down(p, 16);
            if (lane < 16) atomicAdd(&pool_l[wn * 64 + ni * 16 + lane], p);
        }
    }
    __syncthreads();
    // P9: write pooled mean
    if (t < 256) P[(size_t)g * 256 + t] = pool_l[t] * (1.0f / 30.0f);
}

// ---------------- split-bf16 MFMA GEMM (cell1), pre-split X ----------------
template<int NT>
__global__ __launch_bounds__(256) void k_mgemm(const u16* __restrict__ Xs,
        const u16* __restrict__ Wth, const u16* __restrict__ Wtl,
        const float* __restrict__ bias, float* __restrict__ Y,
        int K, int Kp, int F) {
    const int BN = NT * 32;
    __shared__ __align__(16) u16 Xh_l[128 * 40];
    __shared__ __align__(16) u16 Xl_l[128 * 40];
    __shared__ __align__(16) u16 Wh_l[BN * 40];
    __shared__ __align__(16) u16 Wl_l[BN * 40];
    int t = threadIdx.x;
    int row0 = blockIdx.x * 128, col0 = blockIdx.y * BN;
    int wave = t >> 6, lane = t & 63, quad = lane >> 4, l15 = lane & 15;
    int wm = wave >> 1, wn = wave & 1;
    f32x4 acc[4][NT];
#pragma unroll
    for (int mi = 0; mi < 4; mi++)
#pragma unroll
        for (int ni = 0; ni < NT; ni++)
#pragma unroll
            for (int q = 0; q < 4; q++) acc[mi][ni][q] = 0.f;

    int nch = Kp >> 5;
    for (int ch = 0; ch < nch; ch++) {
        int kc = ch << 5;
#pragma unroll
        for (int i = 0; i < 4; i++) {
            int f4 = t + i * 256, r = f4 >> 3, c4 = f4 & 7;
            const u16* rp = Xs + (size_t)(row0 + r) * (2 * K) + kc + c4 * 4;
            *(ushort4*)&Xh_l[r * 40 + c4 * 4] = *(const ushort4*)rp;
            *(ushort4*)&Xl_l[r * 40 + c4 * 4] = *(const ushort4*)(rp + K);
        }
#pragma unroll
        for (int i = 0; i < BN / 32; i++) {
            int f4 = t + i * 256, n = f4 >> 3, c4 = f4 & 7;
            size_t go = (size_t)(col0 + n) * Kp + kc + c4 * 4;
            *(ushort4*)&Wh_l[n * 40 + c4 * 4] = *(const ushort4*)(Wth + go);
            *(ushort4*)&Wl_l[n * 40 + c4 * 4] = *(const ushort4*)(Wtl + go);
        }
        __syncthreads();
        short8 ah[4], al[4], bh[NT], bl[NT];
#pragma unroll
        for (int mi = 0; mi < 4; mi++) {
            int r = wm * 64 + mi * 16 + l15;
            ah[mi] = *(const short8*)&Xh_l[r * 40 + quad * 8];
            al[mi] = *(const short8*)&Xl_l[r * 40 + quad * 8];
        }
#pragma unroll
        for (int ni = 0; ni < NT; ni++) {
            int c = wn * (BN / 2) + ni * 16 + l15;
            bh[ni] = *(const short8*)&Wh_l[c * 40 + quad * 8];
            bl[ni] = *(const short8*)&Wl_l[c * 40 + quad * 8];
        }
#pragma unroll
        for (int mi = 0; mi < 4; mi++)
#pragma unroll
            for (int ni = 0; ni < NT; ni++) {
                acc[mi][ni] = MFMA(ah[mi], bh[ni], acc[mi][ni]);
                acc[mi][ni] = MFMA(al[mi], bh[ni], acc[mi][ni]);
                acc[mi][ni] = MFMA(ah[mi], bl[ni], acc[mi][ni]);
            }
        __syncthreads();
    }
#pragma unroll
    for (int mi = 0; mi < 4; mi++) {
        int row = row0 + wm * 64 + mi * 16 + quad * 4;
#pragma unroll
        for (int ni = 0; ni < NT; ni++) {
            int col = col0 + wn * (BN / 2) + ni * 16 + l15;
            float bv = bias[col];
#pragma unroll
            for (int rg = 0; rg < 4; rg++)
                Y[(size_t)(row + rg) * F + col] = fmaxf(acc[mi][ni][rg] + bv, 0.f);
        }
    }
}

// ---------------- fused tail: drug + cell2 + combiner head, 4 graphs/block ----------------
__global__ __launch_bounds__(256) void k_tail(const float* __restrict__ pooled,
        const float* __restrict__ cell1,
        const float* __restrict__ Wd, const float* __restrict__ bd,
        const float* __restrict__ Wc2, const float* __restrict__ bc2,
        const float* __restrict__ Wm1, const float* __restrict__ bm1,
        const float* __restrict__ Wm2, const float* __restrict__ bm2,
        const float* __restrict__ Wo, const float* __restrict__ bo,
        float* __restrict__ out) {
    __shared__ float pr[1024];   // 4 x 256 pooled
    __shared__ float c1[512];    // 4 x 128 cell1
    __shared__ float dz[512];    // 4 x [drug(64)|cell2(64)]
    __shared__ float z1f[256];   // 4 x 64
    __shared__ float z2f[128];   // 4 x 32
    int t = threadIdx.x;
    int g0 = blockIdx.x * 4;
    int gl = t >> 6, c = t & 63;
    ((float4*)pr)[t] = ((const float4*)(pooled + (size_t)g0 * 256))[t];
    if (t < 128) ((float4*)c1)[t] = ((const float4*)(cell1 + (size_t)g0 * 128))[t];
    __syncthreads();
    float s = bd[c];
#pragma unroll 8
    for (int k = 0; k < 256; k++) s += pr[gl * 256 + k] * Wd[k * 64 + c];
    dz[gl * 128 + c] = s;
    float s2 = bc2[c];
#pragma unroll 8
    for (int k = 0; k < 128; k++) s2 += c1[gl * 128 + k] * Wc2[k * 64 + c];
    dz[gl * 128 + 64 + c] = s2;
    __syncthreads();
    float s3 = bm1[c];
#pragma unroll 8
    for (int k = 0; k < 128; k++) s3 += dz[gl * 128 + k] * Wm1[k * 64 + c];
    z1f[gl * 64 + c] = fmaxf(s3, 0.f);
    __syncthreads();
    if (c < 32) {
        float s4 = bm2[c];
#pragma unroll 8
        for (int k = 0; k < 64; k++) s4 += z1f[gl * 64 + k] * Wm2[k * 32 + c];
        z2f[gl * 32 + c] = fmaxf(s4, 0.f);
    }
    __syncthreads();
    float v = (c < 32) ? z2f[gl * 32 + c] * Wo[c] : 0.f;
#pragma unroll
    for (int off = 32; off > 0; off >>= 1) v += __shfl_down(v, off);
    if (c == 0) out[g0 + gl] = v + bo[0];
}

// ---------------- launch ----------------

extern "C" void kernel_launch(void* const* d_in, const int* in_sizes, int n_in,
                              void* d_out, int out_size, void* d_ws, size_t ws_size,
                              hipStream_t stream) {
    const float* x   = (const float*)d_in[0];
    const int*   ei  = (const int*)d_in[1];
    const float* cf  = (const float*)d_in[3];
    const float* W1  = (const float*)d_in[4];
    const float* b1  = (const float*)d_in[5];
    const float* W2  = (const float*)d_in[6];
    const float* b2  = (const float*)d_in[7];
    const float* W3  = (const float*)d_in[8];
    const float* b3  = (const float*)d_in[9];
    const float* Wd  = (const float*)d_in[10];
    const float* bd  = (const float*)d_in[11];
    const float* Wc1 = (const float*)d_in[12];
    const float* bc1 = (const float*)d_in[13];
    const float* Wc2 = (const float*)d_in[14];
    const float* bc2 = (const float*)d_in[15];
    const float* Wm1 = (const float*)d_in[16];
    const float* bm1 = (const float*)d_in[17];
    const float* Wm2 = (const float*)d_in[18];
    const float* bm2 = (const float*)d_in[19];
    const float* Wo  = (const float*)d_in[20];
    const float* bo  = (const float*)d_in[21];
    float* out = (float*)d_out;

    const int N = in_sizes[0] / 78;    // 245760
    const int E = in_sizes[1] / 2;     // 1,000,000
    const int B = in_sizes[3] / 1000;  // 8192

    char* w = (char*)d_ws;
    auto carve = [&](size_t bytes) { void* p = (void*)w; w += (bytes + 255) & ~(size_t)255; return p; };
    int*   deg    = (int*)  carve((size_t)N * 4);
    int*   ecnt   = (int*)  carve((size_t)B * 4);
    int*   estart = (int*)  carve((size_t)B * 4);
    int*   ecur   = (int*)  carve((size_t)B * 4);
    unsigned short* sE = (unsigned short*)carve((size_t)E * 2);
    float* pooled = (float*)carve((size_t)B * 256 * 4);
    float* cell1  = (float*)carve((size_t)B * 128 * 4);
    u16* W1th = (u16*)carve(64 * 96 * 2);     u16* W1tl = (u16*)carve(64 * 96 * 2);
    u16* W2th = (u16*)carve(128 * 64 * 2);    u16* W2tl = (u16*)carve(128 * 64 * 2);
    u16* W3th = (u16*)carve(256 * 128 * 2);   u16* W3tl = (u16*)carve(256 * 128 * 2);
    u16* Wc1th = (u16*)carve(128 * 1024 * 2); u16* Wc1tl = (u16*)carve(128 * 1024 * 2);
    u16* cfs = (u16*)carve((size_t)B * 2048 * 2);

    auto g1 = [](int n) { return (n + 255) / 256; };

    // prep: degrees -> per-graph counts/offsets -> bucketed edge list
    k_zero_int<<<g1(N), 256, 0, stream>>>(deg, N);
    k_deg<<<g1(E), 256, 0, stream>>>(ei + E, deg, E);
    k_scan<<<1, 1024, 0, stream>>>(deg, ecnt, estart, ecur);
    k_bucket<<<g1(E), 256, 0, stream>>>(ei, ecur, sE, E);

    // weight/feature pre-split
    k_split_t<<<g1(64 * 96), 256, 0, stream>>>(W1, W1th, W1tl, 78, 64, 96);
    k_split_t<<<g1(128 * 64), 256, 0, stream>>>(W2, W2th, W2tl, 64, 128, 64);
    k_split_t<<<g1(256 * 128), 256, 0, stream>>>(W3, W3th, W3tl, 128, 256, 128);
    k_split_t<<<g1(128 * 1024), 256, 0, stream>>>(Wc1, Wc1th, Wc1tl, 1000, 128, 1024);
    k_split_rows<<<g1(B * 1024), 256, 0, stream>>>(cf, cfs, B);

    // fused GCN pipeline: one block per graph
    k_node<<<B, 512, 0, stream>>>(x, deg, sE, estart, ecnt,
                                  W1th, W1tl, W2th, W2tl, W3th, W3tl,
                                  b1, b2, b3, pooled);

    // cell MLP layer 1 (MFMA)
    k_mgemm<2><<<dim3(B / 128, 2), 256, 0, stream>>>(cfs, Wc1th, Wc1tl, bc1, cell1, 1024, 1024, 128);

    // fused tail: drug embed + cell2 + combiner head
    k_tail<<<B / 4, 256, 0, stream>>>(pooled, cell1, Wd, bd, Wc2, bc2,
                                      Wm1, bm1, Wm2, bm2, Wo, bo, out);
}

// Round 6
// 497.506 us; speedup vs baseline: 9.4976x; 1.4182x over previous
//
#include <hip/hip_runtime.h>

typedef __attribute__((ext_vector_type(8))) short short8;
typedef __attribute__((ext_vector_type(4))) short short4v;
typedef __attribute__((ext_vector_type(4))) float f32x4;
typedef unsigned short u16;

__device__ __forceinline__ u16 f2bf(float f) {
    union { float f; unsigned u; } v; v.f = f;
    unsigned r = v.u + 0x7FFFu + ((v.u >> 16) & 1u);
    return (u16)(r >> 16);
}
__device__ __forceinline__ float bf2f(u16 h) {
    union { unsigned u; float f; } v; v.u = ((unsigned)h) << 16;
    return v.f;
}
__device__ __forceinline__ void split2(float f, u16& h, u16& l) {
    h = f2bf(f);
    l = f2bf(f - bf2f(h));
}
// 8-byte-aligned LDS frag load
__device__ __forceinline__ short8 ld8(const u16* p) {
    short4v a = *(const short4v*)p;
    short4v b = *(const short4v*)(p + 4);
    short8 r;
    r[0] = a[0]; r[1] = a[1]; r[2] = a[2]; r[3] = a[3];
    r[4] = b[0]; r[5] = b[1]; r[6] = b[2]; r[7] = b[3];
    return r;
}
#define MFMA(A, B, C) __builtin_amdgcn_mfma_f32_16x16x32_bf16(A, B, C, 0, 0, 0)

// ---------------- prep kernels ----------------

__global__ void k_zero4(int4* __restrict__ p, int n4) {
    int i = blockIdx.x * 256 + threadIdx.x;
    if (i < n4) p[i] = make_int4(0, 0, 0, 0);
}

// per-graph 30x32 adjacency count matrix: Acnt[g][dl][sl] += 1
__global__ void k_cnt(const int* __restrict__ ei, int* __restrict__ Acnt, int E) {
    int e = blockIdx.x * 256 + threadIdx.x;
    if (e >= E) return;
    int s = ei[e], d = ei[E + e];
    int g = d / 30;
    atomicAdd(&Acnt[(size_t)g * 960 + (d - g * 30) * 32 + (s - g * 30)], 1);
}

// split fp32 W[K][F] -> transposed hi/lo bf16 [F][Kp], zero-padded K->Kp
__global__ void k_split_t(const float* __restrict__ W, u16* __restrict__ th,
                          u16* __restrict__ tl, int K, int F, int Kp) {
    int idx = blockIdx.x * 256 + threadIdx.x;
    if (idx >= F * Kp) return;
    int f = idx / Kp, k = idx % Kp;
    float v = (k < K) ? W[(size_t)k * F + f] : 0.f;
    u16 h, l; split2(v, h, l);
    th[idx] = h; tl[idx] = l;
}

// split cf rows: [B][1000] fp32 -> [B][2048] u16 (hi 0..1023 | lo 1024..2047)
__global__ void k_split_rows(const float* __restrict__ cf, u16* __restrict__ o, int B) {
    int idx = blockIdx.x * 256 + threadIdx.x;
    if (idx >= B * 1024) return;
    int r = idx >> 10, c = idx & 1023;
    float v = (c < 1000) ? cf[(size_t)r * 1000 + c] : 0.f;
    u16 h, l; split2(v, h, l);
    o[(size_t)r * 2048 + c] = h;
    o[(size_t)r * 2048 + 1024 + c] = l;
}

// ---------------- fused node pipeline: one block per graph ----------------
// column-slice wave mapping: W frags read exactly once per block.
__global__ __launch_bounds__(512, 6) void k_node(
    const float* __restrict__ x, const int* __restrict__ Acnt,
    const u16* __restrict__ W1h, const u16* __restrict__ W1l,
    const u16* __restrict__ W2h, const u16* __restrict__ W2l,
    const u16* __restrict__ W3h, const u16* __restrict__ W3l,
    const float* __restrict__ b1, const float* __restrict__ b2,
    const float* __restrict__ b3, float* __restrict__ P) {
    __shared__ __align__(16) char smem[46976];
    u16* xh  = (u16*)(smem + 0);         // [32][100]  Ph1-Ph4
    u16* xl  = (u16*)(smem + 6400);
    u16* h1h = (u16*)(smem + 0);         // [32][68]   Ph5-Ph6 (over x)
    u16* h1l = (u16*)(smem + 4352);
    u16* a3h = (u16*)(smem + 0);         // [32][132]  Ph7-Ph8 (over h1)
    u16* a3l = (u16*)(smem + 8448);
    u16* t1h = (u16*)(smem + 16896);     // [64][36]   Ph4-Ph5
    u16* t1l = (u16*)(smem + 21504);
    u16* h2h = (u16*)(smem + 16896);     // [128][36]  Ph6-Ph7 (over t1T)
    u16* h2l = (u16*)(smem + 26112);
    float* Afp  = (float*)(smem + 35328); // [30][32]
    u16* Ah  = (u16*)(smem + 39424);     // [32][36]
    u16* Al  = (u16*)(smem + 41728);
    float* dv   = (float*)(smem + 44032); // [32]
    float* pool = (float*)(smem + 44160); // [256]
    float* bias = (float*)(smem + 45184); // [448]

    int t = threadIdx.x;
    int g = blockIdx.x;
    int wave = t >> 6, lane = t & 63, quad = lane >> 4, l15 = lane & 15;

    // Ph0: zero x region (pads), load biases
    {
        uint* zp = (uint*)smem;
        for (int i = t; i < 3200; i += 512) zp[i] = 0;
        if (t < 448) bias[t] = (t < 64) ? b1[t] : (t < 192 ? b2[t - 64] : b3[t - 192]);
    }
    __syncthreads();
    // Ph1: stage x split hi/lo; stage Acnt as float
    {
        const float4* xg = (const float4*)(x + (size_t)g * 2340);
        for (int i = t; i < 585; i += 512) {
            float4 v = xg[i];
            int base = i * 4;
            float vv[4] = {v.x, v.y, v.z, v.w};
#pragma unroll
            for (int j = 0; j < 4; j++) {
                int idx = base + j;
                int r = idx / 78, c = idx - r * 78;
                u16 h, l; split2(vv[j], h, l);
                xh[r * 100 + c] = h; xl[r * 100 + c] = l;
            }
        }
        const int* ac = Acnt + (size_t)g * 960;
        for (int i = t; i < 960; i += 512) Afp[i] = (float)ac[i];
    }
    __syncthreads();
    // Ph2: deg row-sums -> dv
    if (t < 32) {
        float s = 0.f;
        if (t < 30)
            for (int j = 0; j < 32; j++) s += Afp[t * 32 + j];
        dv[t] = (t < 30) ? rsqrtf(s + 1.f) : 0.f;
    }
    __syncthreads();
    // Ph3: A = (cnt + I) * dv_d * dv_s, split -> Ah/Al; zero pad rows
    {
        for (int i = t; i < 960; i += 512) {
            int r = i >> 5, c = i & 31;
            float a = (Afp[i] + (r == c ? 1.f : 0.f)) * dv[r] * dv[c];
            u16 h, l; split2(a, h, l);
            Ah[r * 36 + c] = h; Al[r * 36 + c] = l;
        }
        if (t < 64) {
            int r = 30 + (t >> 5), c = t & 31;
            Ah[r * 36 + c] = 0; Al[r * 36 + c] = 0;
        }
    }
    __syncthreads();
    // Ph4: GEMM1  t1 = x @ W1  (M=32, N=64, K=96) -> t1T
    {
        int wm = wave >> 2, wn = wave & 3;
        int arow = wm * 16 + l15;
        int col = wn * 16 + l15;
        const u16* wph = W1h + col * 96 + quad * 8;
        const u16* wpl = W1l + col * 96 + quad * 8;
        f32x4 acc = {0.f, 0.f, 0.f, 0.f};
#pragma unroll
        for (int ch = 0; ch < 3; ch++) {
            int kc = ch * 32;
            short8 bh = *(const short8*)(wph + kc);
            short8 bl = *(const short8*)(wpl + kc);
            short8 ah = ld8(&xh[arow * 100 + kc + quad * 8]);
            short8 al = ld8(&xl[arow * 100 + kc + quad * 8]);
            acc = MFMA(ah, bh, acc);
            acc = MFMA(al, bh, acc);
            acc = MFMA(ah, bl, acc);
        }
#pragma unroll
        for (int rg = 0; rg < 4; rg++) {
            int row = wm * 16 + quad * 4 + rg;
            u16 h, l; split2(acc[rg], h, l);
            t1h[col * 36 + row] = h;
            t1l[col * 36 + row] = l;
        }
    }
    __syncthreads();
    // Ph5: agg1  h1 = relu(A @ t1 + b1)  (M=32, N=64, K=32)
    {
        int wm = wave >> 2, wn = wave & 3;
        int arow = wm * 16 + l15;
        int col = wn * 16 + l15;
        short8 aAh = ld8(&Ah[arow * 36 + quad * 8]);
        short8 aAl = ld8(&Al[arow * 36 + quad * 8]);
        short8 bh = ld8(&t1h[col * 36 + quad * 8]);
        short8 bl = ld8(&t1l[col * 36 + quad * 8]);
        f32x4 acc = {0.f, 0.f, 0.f, 0.f};
        acc = MFMA(aAh, bh, acc);
        acc = MFMA(aAl, bh, acc);
        acc = MFMA(aAh, bl, acc);
        float bb = bias[col];
#pragma unroll
        for (int rg = 0; rg < 4; rg++) {
            int row = wm * 16 + quad * 4 + rg;
            float v = fmaxf(acc[rg] + bb, 0.f);
            u16 h, l; split2(v, h, l);
            h1h[row * 68 + col] = h;
            h1l[row * 68 + col] = l;
        }
    }
    __syncthreads();
    // Ph6: GEMM2  h2 = relu(h1 @ W2 + b2)  (M=32, N=128, K=64) -> h2T
    {
        int col = wave * 16 + l15;
        const u16* wph = W2h + col * 64 + quad * 8;
        const u16* wpl = W2l + col * 64 + quad * 8;
        f32x4 acc[2] = {{0.f,0.f,0.f,0.f},{0.f,0.f,0.f,0.f}};
#pragma unroll
        for (int ch = 0; ch < 2; ch++) {
            int kc = ch * 32;
            short8 bh = *(const short8*)(wph + kc);
            short8 bl = *(const short8*)(wpl + kc);
#pragma unroll
            for (int mi = 0; mi < 2; mi++) {
                short8 ah = ld8(&h1h[(mi * 16 + l15) * 68 + kc + quad * 8]);
                short8 al = ld8(&h1l[(mi * 16 + l15) * 68 + kc + quad * 8]);
                acc[mi] = MFMA(ah, bh, acc[mi]);
                acc[mi] = MFMA(al, bh, acc[mi]);
                acc[mi] = MFMA(ah, bl, acc[mi]);
            }
        }
        float bb = bias[64 + col];
#pragma unroll
        for (int mi = 0; mi < 2; mi++)
#pragma unroll
            for (int rg = 0; rg < 4; rg++) {
                int row = mi * 16 + quad * 4 + rg;
                float v = fmaxf(acc[mi][rg] + bb, 0.f);
                u16 h, l; split2(v, h, l);
                h2h[col * 36 + row] = h;
                h2l[col * 36 + row] = l;
            }
    }
    __syncthreads();
    // Ph7: agg2  a3 = A @ h2  (M=32, N=128, K=32)
    {
        int col = wave * 16 + l15;
        short8 bh = ld8(&h2h[col * 36 + quad * 8]);
        short8 bl = ld8(&h2l[col * 36 + quad * 8]);
        f32x4 acc[2] = {{0.f,0.f,0.f,0.f},{0.f,0.f,0.f,0.f}};
#pragma unroll
        for (int mi = 0; mi < 2; mi++) {
            short8 aAh = ld8(&Ah[(mi * 16 + l15) * 36 + quad * 8]);
            short8 aAl = ld8(&Al[(mi * 16 + l15) * 36 + quad * 8]);
            acc[mi] = MFMA(aAh, bh, acc[mi]);
            acc[mi] = MFMA(aAl, bh, acc[mi]);
            acc[mi] = MFMA(aAh, bl, acc[mi]);
        }
#pragma unroll
        for (int mi = 0; mi < 2; mi++)
#pragma unroll
            for (int rg = 0; rg < 4; rg++) {
                int row = mi * 16 + quad * 4 + rg;
                u16 h, l; split2(acc[mi][rg], h, l);
                a3h[row * 132 + col] = h;
                a3l[row * 132 + col] = l;
            }
    }
    __syncthreads();
    // Ph8: GEMM3 + pool  (M=32, N=256, K=128), W3 frags double-buffered
    {
        int colb = wave * 32;
        f32x4 acc[2][2] = {{{0.f,0.f,0.f,0.f},{0.f,0.f,0.f,0.f}},
                           {{0.f,0.f,0.f,0.f},{0.f,0.f,0.f,0.f}}};
        short8 cwh[2], cwl[2], nwh[2], nwl[2];
#pragma unroll
        for (int ni = 0; ni < 2; ni++) {
            size_t o = (size_t)(colb + ni * 16 + l15) * 128 + quad * 8;
            cwh[ni] = *(const short8*)(W3h + o);
            cwl[ni] = *(const short8*)(W3l + o);
        }
#pragma unroll
        for (int ch = 0; ch < 4; ch++) {
            if (ch < 3) {
#pragma unroll
                for (int ni = 0; ni < 2; ni++) {
                    size_t o = (size_t)(colb + ni * 16 + l15) * 128 + (ch + 1) * 32 + quad * 8;
                    nwh[ni] = *(const short8*)(W3h + o);
                    nwl[ni] = *(const short8*)(W3l + o);
                }
            }
            short8 ah[2], al[2];
#pragma unroll
            for (int mi = 0; mi < 2; mi++) {
                ah[mi] = ld8(&a3h[(mi * 16 + l15) * 132 + ch * 32 + quad * 8]);
                al[mi] = ld8(&a3l[(mi * 16 + l15) * 132 + ch * 32 + quad * 8]);
            }
#pragma unroll
            for (int mi = 0; mi < 2; mi++)
#pragma unroll
                for (int ni = 0; ni < 2; ni++) {
                    acc[mi][ni] = MFMA(ah[mi], cwh[ni], acc[mi][ni]);
                    acc[mi][ni] = MFMA(al[mi], cwh[ni], acc[mi][ni]);
                    acc[mi][ni] = MFMA(ah[mi], cwl[ni], acc[mi][ni]);
                }
            if (ch < 3) {
#pragma unroll
                for (int ni = 0; ni < 2; ni++) { cwh[ni] = nwh[ni]; cwl[ni] = nwl[ni]; }
            }
        }
        // pool: per-column reduce across quads (cols disjoint per wave -> no atomics)
#pragma unroll
        for (int ni = 0; ni < 2; ni++) {
            int col = colb + ni * 16 + l15;
            float bb = bias[192 + col];
            float p = 0.f;
#pragma unroll
            for (int mi = 0; mi < 2; mi++)
#pragma unroll
                for (int rg = 0; rg < 4; rg++) {
                    int row = mi * 16 + quad * 4 + rg;
                    if (row < 30) p += fmaxf(acc[mi][ni][rg] + bb, 0.f);
                }
            p += __shfl_down(p, 32);
            p += __shfl_down(p, 16);
            if (lane < 16) pool[colb + ni * 16 + lane] = p;
        }
    }
    __syncthreads();
    // Ph9: write pooled mean
    if (t < 256) P[(size_t)g * 256 + t] = pool[t] * (1.0f / 30.0f);
}

// ---------------- split-bf16 MFMA GEMM (cell1), pre-split X ----------------
template<int NT>
__global__ __launch_bounds__(256) void k_mgemm(const u16* __restrict__ Xs,
        const u16* __restrict__ Wth, const u16* __restrict__ Wtl,
        const float* __restrict__ bias, float* __restrict__ Y,
        int K, int Kp, int F) {
    const int BN = NT * 32;
    __shared__ __align__(16) u16 Xh_l[128 * 40];
    __shared__ __align__(16) u16 Xl_l[128 * 40];
    __shared__ __align__(16) u16 Wh_l[BN * 40];
    __shared__ __align__(16) u16 Wl_l[BN * 40];
    int t = threadIdx.x;
    int row0 = blockIdx.x * 128, col0 = blockIdx.y * BN;
    int wave = t >> 6, lane = t & 63, quad = lane >> 4, l15 = lane & 15;
    int wm = wave >> 1, wn = wave & 1;
    f32x4 acc[4][NT];
#pragma unroll
    for (int mi = 0; mi < 4; mi++)
#pragma unroll
        for (int ni = 0; ni < NT; ni++)
#pragma unroll
            for (int q = 0; q < 4; q++) acc[mi][ni][q] = 0.f;

    int nch = Kp >> 5;
    for (int ch = 0; ch < nch; ch++) {
        int kc = ch << 5;
#pragma unroll
        for (int i = 0; i < 4; i++) {
            int f4 = t + i * 256, r = f4 >> 3, c4 = f4 & 7;
            const u16* rp = Xs + (size_t)(row0 + r) * (2 * K) + kc + c4 * 4;
            *(ushort4*)&Xh_l[r * 40 + c4 * 4] = *(const ushort4*)rp;
            *(ushort4*)&Xl_l[r * 40 + c4 * 4] = *(const ushort4*)(rp + K);
        }
#pragma unroll
        for (int i = 0; i < BN / 32; i++) {
            int f4 = t + i * 256, n = f4 >> 3, c4 = f4 & 7;
            size_t go = (size_t)(col0 + n) * Kp + kc + c4 * 4;
            *(ushort4*)&Wh_l[n * 40 + c4 * 4] = *(const ushort4*)(Wth + go);
            *(ushort4*)&Wl_l[n * 40 + c4 * 4] = *(const ushort4*)(Wtl + go);
        }
        __syncthreads();
        short8 ah[4], al[4], bh[NT], bl[NT];
#pragma unroll
        for (int mi = 0; mi < 4; mi++) {
            int r = wm * 64 + mi * 16 + l15;
            ah[mi] = *(const short8*)&Xh_l[r * 40 + quad * 8];
            al[mi] = *(const short8*)&Xl_l[r * 40 + quad * 8];
        }
#pragma unroll
        for (int ni = 0; ni < NT; ni++) {
            int c = wn * (BN / 2) + ni * 16 + l15;
            bh[ni] = *(const short8*)&Wh_l[c * 40 + quad * 8];
            bl[ni] = *(const short8*)&Wl_l[c * 40 + quad * 8];
        }
#pragma unroll
        for (int mi = 0; mi < 4; mi++)
#pragma unroll
            for (int ni = 0; ni < NT; ni++) {
                acc[mi][ni] = MFMA(ah[mi], bh[ni], acc[mi][ni]);
                acc[mi][ni] = MFMA(al[mi], bh[ni], acc[mi][ni]);
                acc[mi][ni] = MFMA(ah[mi], bl[ni], acc[mi][ni]);
            }
        __syncthreads();
    }
#pragma unroll
    for (int mi = 0; mi < 4; mi++) {
        int row = row0 + wm * 64 + mi * 16 + quad * 4;
#pragma unroll
        for (int ni = 0; ni < NT; ni++) {
            int col = col0 + wn * (BN / 2) + ni * 16 + l15;
            float bv = bias[col];
#pragma unroll
            for (int rg = 0; rg < 4; rg++)
                Y[(size_t)(row + rg) * F + col] = fmaxf(acc[mi][ni][rg] + bv, 0.f);
        }
    }
}

// ---------------- fused tail: drug + cell2 + combiner head, 4 graphs/block ----------------
__global__ __launch_bounds__(256) void k_tail(const float* __restrict__ pooled,
        const float* __restrict__ cell1,
        const float* __restrict__ Wd, const float* __restrict__ bd,
        const float* __restrict__ Wc2, const float* __restrict__ bc2,
        const float* __restrict__ Wm1, const float* __restrict__ bm1,
        const float* __restrict__ Wm2, const float* __restrict__ bm2,
        const float* __restrict__ Wo, const float* __restrict__ bo,
        float* __restrict__ out) {
    __shared__ float pr[1024];
    __shared__ float c1[512];
    __shared__ float dz[512];
    __shared__ float z1f[256];
    __shared__ float z2f[128];
    int t = threadIdx.x;
    int g0 = blockIdx.x * 4;
    int gl = t >> 6, c = t & 63;
    ((float4*)pr)[t] = ((const float4*)(pooled + (size_t)g0 * 256))[t];
    if (t < 128) ((float4*)c1)[t] = ((const float4*)(cell1 + (size_t)g0 * 128))[t];
    __syncthreads();
    float s = bd[c];
#pragma unroll 8
    for (int k = 0; k < 256; k++) s += pr[gl * 256 + k] * Wd[k * 64 + c];
    dz[gl * 128 + c] = s;
    float s2 = bc2[c];
#pragma unroll 8
    for (int k = 0; k < 128; k++) s2 += c1[gl * 128 + k] * Wc2[k * 64 + c];
    dz[gl * 128 + 64 + c] = s2;
    __syncthreads();
    float s3 = bm1[c];
#pragma unroll 8
    for (int k = 0; k < 128; k++) s3 += dz[gl * 128 + k] * Wm1[k * 64 + c];
    z1f[gl * 64 + c] = fmaxf(s3, 0.f);
    __syncthreads();
    if (c < 32) {
        float s4 = bm2[c];
#pragma unroll 8
        for (int k = 0; k < 64; k++) s4 += z1f[gl * 64 + k] * Wm2[k * 32 + c];
        z2f[gl * 32 + c] = fmaxf(s4, 0.f);
    }
    __syncthreads();
    float v = (c < 32) ? z2f[gl * 32 + c] * Wo[c] : 0.f;
#pragma unroll
    for (int off = 32; off > 0; off >>= 1) v += __shfl_down(v, off);
    if (c == 0) out[g0 + gl] = v + bo[0];
}

// ---------------- launch ----------------

extern "C" void kernel_launch(void* const* d_in, const int* in_sizes, int n_in,
                              void* d_out, int out_size, void* d_ws, size_t ws_size,
                              hipStream_t stream) {
    const float* x   = (const float*)d_in[0];
    const int*   ei  = (const int*)d_in[1];
    const float* cf  = (const float*)d_in[3];
    const float* W1  = (const float*)d_in[4];
    const float* b1  = (const float*)d_in[5];
    const float* W2  = (const float*)d_in[6];
    const float* b2  = (const float*)d_in[7];
    const float* W3  = (const float*)d_in[8];
    const float* b3  = (const float*)d_in[9];
    const float* Wd  = (const float*)d_in[10];
    const float* bd  = (const float*)d_in[11];
    const float* Wc1 = (const float*)d_in[12];
    const float* bc1 = (const float*)d_in[13];
    const float* Wc2 = (const float*)d_in[14];
    const float* bc2 = (const float*)d_in[15];
    const float* Wm1 = (const float*)d_in[16];
    const float* bm1 = (const float*)d_in[17];
    const float* Wm2 = (const float*)d_in[18];
    const float* bm2 = (const float*)d_in[19];
    const float* Wo  = (const float*)d_in[20];
    const float* bo  = (const float*)d_in[21];
    float* out = (float*)d_out;

    const int E = in_sizes[1] / 2;     // 1,000,000
    const int B = in_sizes[3] / 1000;  // 8192

    char* w = (char*)d_ws;
    auto carve = [&](size_t bytes) { void* p = (void*)w; w += (bytes + 255) & ~(size_t)255; return p; };
    int*   Acnt   = (int*)  carve((size_t)B * 960 * 4);   // 31.5 MB
    float* pooled = (float*)carve((size_t)B * 256 * 4);
    float* cell1  = (float*)carve((size_t)B * 128 * 4);
    u16* W1th = (u16*)carve(64 * 96 * 2);     u16* W1tl = (u16*)carve(64 * 96 * 2);
    u16* W2th = (u16*)carve(128 * 64 * 2);    u16* W2tl = (u16*)carve(128 * 64 * 2);
    u16* W3th = (u16*)carve(256 * 128 * 2);   u16* W3tl = (u16*)carve(256 * 128 * 2);
    u16* Wc1th = (u16*)carve(128 * 1024 * 2); u16* Wc1tl = (u16*)carve(128 * 1024 * 2);
    u16* cfs = (u16*)carve((size_t)B * 2048 * 2);

    auto g1 = [](int n) { return (n + 255) / 256; };

    // prep: one-pass adjacency count matrices
    k_zero4<<<g1(B * 240), 256, 0, stream>>>((int4*)Acnt, B * 240);
    k_cnt<<<g1(E), 256, 0, stream>>>(ei, Acnt, E);

    // weight/feature pre-split
    k_split_t<<<g1(64 * 96), 256, 0, stream>>>(W1, W1th, W1tl, 78, 64, 96);
    k_split_t<<<g1(128 * 64), 256, 0, stream>>>(W2, W2th, W2tl, 64, 128, 64);
    k_split_t<<<g1(256 * 128), 256, 0, stream>>>(W3, W3th, W3tl, 128, 256, 128);
    k_split_t<<<g1(128 * 1024), 256, 0, stream>>>(Wc1, Wc1th, Wc1tl, 1000, 128, 1024);
    k_split_rows<<<g1(B * 1024), 256, 0, stream>>>(cf, cfs, B);

    // fused GCN pipeline: one block per graph
    k_node<<<B, 512, 0, stream>>>(x, Acnt,
                                  W1th, W1tl, W2th, W2tl, W3th, W3tl,
                                  b1, b2, b3, pooled);

    // cell MLP layer 1 (MFMA)
    k_mgemm<1><<<dim3(B / 128, 4), 256, 0, stream>>>(cfs, Wc1th, Wc1tl, bc1, cell1, 1024, 1024, 128);

    // fused tail: drug embed + cell2 + combiner head
    k_tail<<<B / 4, 256, 0, stream>>>(pooled, cell1, Wd, bd, Wc2, bc2,
                                      Wm1, bm1, Wm2, bm2, Wo, bo, out);
}

// Round 7
// 476.483 us; speedup vs baseline: 9.9166x; 1.0441x over previous
//
#include <hip/hip_runtime.h>

typedef __attribute__((ext_vector_type(8))) short short8;
typedef __attribute__((ext_vector_type(4))) short short4v;
typedef __attribute__((ext_vector_type(4))) float f32x4;
typedef unsigned short u16;

__device__ __forceinline__ u16 f2bf(float f) {
    union { float f; unsigned u; } v; v.f = f;
    unsigned r = v.u + 0x7FFFu + ((v.u >> 16) & 1u);
    return (u16)(r >> 16);
}
__device__ __forceinline__ float bf2f(u16 h) {
    union { unsigned u; float f; } v; v.u = ((unsigned)h) << 16;
    return v.f;
}
__device__ __forceinline__ void split2(float f, u16& h, u16& l) {
    h = f2bf(f);
    l = f2bf(f - bf2f(h));
}
// 8-byte-aligned LDS frag load
__device__ __forceinline__ short8 ld8(const u16* p) {
    short4v a = *(const short4v*)p;
    short4v b = *(const short4v*)(p + 4);
    short8 r;
    r[0] = a[0]; r[1] = a[1]; r[2] = a[2]; r[3] = a[3];
    r[4] = b[0]; r[5] = b[1]; r[6] = b[2]; r[7] = b[3];
    return r;
}
#define MFMA(A, B, C) __builtin_amdgcn_mfma_f32_16x16x32_bf16(A, B, C, 0, 0, 0)

// ---------------- prep kernels ----------------

__global__ void k_zero4(int4* __restrict__ p, int n4) {
    int i = blockIdx.x * 256 + threadIdx.x;
    if (i < n4) p[i] = make_int4(0, 0, 0, 0);
}

// per-graph 30x32 adjacency count matrix, u16 packed in u32 pairs
__global__ void k_cnt(const int* __restrict__ ei, unsigned* __restrict__ A32, int E) {
    int e = blockIdx.x * 256 + threadIdx.x;
    if (e >= E) return;
    int s = ei[e], d = ei[E + e];
    int g = d / 30;
    int idx = g * 960 + (d - g * 30) * 32 + (s - g * 30);
    atomicAdd(&A32[idx >> 1], 1u << ((idx & 1) * 16));
}

// split fp32 W[K][F] -> transposed hi/lo bf16 [F][Kp], zero-padded K->Kp
__global__ void k_split_t(const float* __restrict__ W, u16* __restrict__ th,
                          u16* __restrict__ tl, int K, int F, int Kp) {
    int idx = blockIdx.x * 256 + threadIdx.x;
    if (idx >= F * Kp) return;
    int f = idx / Kp, k = idx % Kp;
    float v = (k < K) ? W[(size_t)k * F + f] : 0.f;
    u16 h, l; split2(v, h, l);
    th[idx] = h; tl[idx] = l;
}

// ---------------- fused node pipeline: one block per graph, 4 blocks/CU ----------------
__global__ __launch_bounds__(512, 8) void k_node(
    const float* __restrict__ x, const unsigned* __restrict__ A32,
    const u16* __restrict__ W1h, const u16* __restrict__ W1l,
    const u16* __restrict__ W2h, const u16* __restrict__ W2l,
    const u16* __restrict__ W3h, const u16* __restrict__ W3l,
    const float* __restrict__ b1, const float* __restrict__ b2,
    const float* __restrict__ b3, float* __restrict__ P) {
    __shared__ __align__(16) char smem[39936];
    // region1 (0..16896): x [32][100] h/l | h1 [32][68] h/l | a3 [32][132] h/l
    u16* xh  = (u16*)(smem + 0);
    u16* xl  = (u16*)(smem + 6400);
    u16* h1h = (u16*)(smem + 0);
    u16* h1l = (u16*)(smem + 4352);
    u16* a3h = (u16*)(smem + 0);
    u16* a3l = (u16*)(smem + 8448);
    // region2 (16896..35328): Afp[30][32]+dv | t1T [64][36] h/l | h2T [128][36] h/l
    float* Afp = (float*)(smem + 16896);
    float* dv  = (float*)(smem + 20736);
    u16* t1h = (u16*)(smem + 16896);
    u16* t1l = (u16*)(smem + 21504);
    u16* h2h = (u16*)(smem + 16896);
    u16* h2l = (u16*)(smem + 26112);
    // region3 (35328..39936): A [32][36] h/l
    u16* Ah  = (u16*)(smem + 35328);
    u16* Al  = (u16*)(smem + 37632);

    int t = threadIdx.x;
    int g = blockIdx.x;
    int wave = t >> 6, lane = t & 63, quad = lane >> 4, l15 = lane & 15;

    // Ph1: zero x pads; stage x split; stage Afp; dv from global counts
    {
        // zero pads: rows 0..29 u32-cols 39..49 (u16 78..99), rows 30..31 full
        for (int i = t; i < 860; i += 512) {
            uint* arr = (uint*)((i >= 430) ? (char*)xl : (char*)xh);
            int j = (i >= 430) ? i - 430 : i;
            int r, c32;
            if (j < 330) { r = j / 11; c32 = 39 + j % 11; }
            else { r = 30 + (j - 330) / 50; c32 = (j - 330) % 50; }
            arr[r * 50 + c32] = 0;
        }
        const float4* xg = (const float4*)(x + (size_t)g * 2340);
        for (int i = t; i < 585; i += 512) {
            float4 v = xg[i];
            int base = i * 4;
            float vv[4] = {v.x, v.y, v.z, v.w};
#pragma unroll
            for (int j = 0; j < 4; j++) {
                int idx = base + j;
                int r = idx / 78, c = idx - r * 78;
                u16 h, l; split2(vv[j], h, l);
                xh[r * 100 + c] = h; xl[r * 100 + c] = l;
            }
        }
        const unsigned* ac = A32 + (size_t)g * 480;
        for (int i = t; i < 480; i += 512) {
            unsigned w = ac[i];
            Afp[2 * i] = (float)(w & 0xFFFFu);
            Afp[2 * i + 1] = (float)(w >> 16);
        }
        if (t < 32) {
            float s = 1.f;
            if (t < 30) {
                const unsigned* rp = ac + t * 16;
                unsigned acc = 0;
#pragma unroll
                for (int j = 0; j < 16; j++) { unsigned w = rp[j]; acc += (w & 0xFFFFu) + (w >> 16); }
                s += (float)acc;
            }
            dv[t] = (t < 30) ? rsqrtf(s) : 0.f;
        }
    }
    __syncthreads();
    // Ph3: A = (cnt + I) * dv_d * dv_s -> Ah/Al (pad rows/cols -> 0)
    {
#pragma unroll
        for (int ii = 0; ii < 2; ii++) {
            int i = t + ii * 512;
            int r = i >> 5, c = i & 31;
            float a = 0.f;
            if (r < 30 && c < 30)
                a = (Afp[r * 32 + c] + (r == c ? 1.f : 0.f)) * dv[r] * dv[c];
            u16 h, l; split2(a, h, l);
            Ah[r * 36 + c] = h; Al[r * 36 + c] = l;
        }
    }
    __syncthreads();
    // Ph4: GEMM1  t1 = x @ W1  (M=32, N=64, K=96) -> t1T
    {
        int wm = wave >> 2, wn = wave & 3;
        int arow = wm * 16 + l15;
        int col = wn * 16 + l15;
        const u16* wph = W1h + col * 96 + quad * 8;
        const u16* wpl = W1l + col * 96 + quad * 8;
        f32x4 acc = {0.f, 0.f, 0.f, 0.f};
#pragma unroll
        for (int ch = 0; ch < 3; ch++) {
            int kc = ch * 32;
            short8 bh = *(const short8*)(wph + kc);
            short8 bl = *(const short8*)(wpl + kc);
            short8 ah = ld8(&xh[arow * 100 + kc + quad * 8]);
            short8 al = ld8(&xl[arow * 100 + kc + quad * 8]);
            acc = MFMA(ah, bh, acc);
            acc = MFMA(al, bh, acc);
            acc = MFMA(ah, bl, acc);
        }
#pragma unroll
        for (int rg = 0; rg < 4; rg++) {
            int row = wm * 16 + quad * 4 + rg;
            u16 h, l; split2(acc[rg], h, l);
            t1h[col * 36 + row] = h;
            t1l[col * 36 + row] = l;
        }
    }
    __syncthreads();
    // Ph5: agg1  h1 = relu(A @ t1 + b1)  (M=32, N=64, K=32)
    {
        int wm = wave >> 2, wn = wave & 3;
        int arow = wm * 16 + l15;
        int col = wn * 16 + l15;
        short8 aAh = ld8(&Ah[arow * 36 + quad * 8]);
        short8 aAl = ld8(&Al[arow * 36 + quad * 8]);
        short8 bh = ld8(&t1h[col * 36 + quad * 8]);
        short8 bl = ld8(&t1l[col * 36 + quad * 8]);
        f32x4 acc = {0.f, 0.f, 0.f, 0.f};
        acc = MFMA(aAh, bh, acc);
        acc = MFMA(aAl, bh, acc);
        acc = MFMA(aAh, bl, acc);
        float bb = b1[col];
#pragma unroll
        for (int rg = 0; rg < 4; rg++) {
            int row = wm * 16 + quad * 4 + rg;
            float v = fmaxf(acc[rg] + bb, 0.f);
            u16 h, l; split2(v, h, l);
            h1h[row * 68 + col] = h;
            h1l[row * 68 + col] = l;
        }
    }
    __syncthreads();
    // Ph6: GEMM2  h2 = relu(h1 @ W2 + b2)  (M=32, N=128, K=64) -> h2T
    {
        int col = wave * 16 + l15;
        const u16* wph = W2h + col * 64 + quad * 8;
        const u16* wpl = W2l + col * 64 + quad * 8;
        f32x4 acc[2] = {{0.f,0.f,0.f,0.f},{0.f,0.f,0.f,0.f}};
#pragma unroll
        for (int ch = 0; ch < 2; ch++) {
            int kc = ch * 32;
            short8 bh = *(const short8*)(wph + kc);
            short8 bl = *(const short8*)(wpl + kc);
#pragma unroll
            for (int mi = 0; mi < 2; mi++) {
                short8 ah = ld8(&h1h[(mi * 16 + l15) * 68 + kc + quad * 8]);
                short8 al = ld8(&h1l[(mi * 16 + l15) * 68 + kc + quad * 8]);
                acc[mi] = MFMA(ah, bh, acc[mi]);
                acc[mi] = MFMA(al, bh, acc[mi]);
                acc[mi] = MFMA(ah, bl, acc[mi]);
            }
        }
        float bb = b2[col];
#pragma unroll
        for (int mi = 0; mi < 2; mi++)
#pragma unroll
            for (int rg = 0; rg < 4; rg++) {
                int row = mi * 16 + quad * 4 + rg;
                float v = fmaxf(acc[mi][rg] + bb, 0.f);
                u16 h, l; split2(v, h, l);
                h2h[col * 36 + row] = h;
                h2l[col * 36 + row] = l;
            }
    }
    __syncthreads();
    // Ph7: agg2  a3 = A @ h2  (M=32, N=128, K=32)
    {
        int col = wave * 16 + l15;
        short8 bh = ld8(&h2h[col * 36 + quad * 8]);
        short8 bl = ld8(&h2l[col * 36 + quad * 8]);
        f32x4 acc[2] = {{0.f,0.f,0.f,0.f},{0.f,0.f,0.f,0.f}};
#pragma unroll
        for (int mi = 0; mi < 2; mi++) {
            short8 aAh = ld8(&Ah[(mi * 16 + l15) * 36 + quad * 8]);
            short8 aAl = ld8(&Al[(mi * 16 + l15) * 36 + quad * 8]);
            acc[mi] = MFMA(aAh, bh, acc[mi]);
            acc[mi] = MFMA(aAl, bh, acc[mi]);
            acc[mi] = MFMA(aAh, bl, acc[mi]);
        }
#pragma unroll
        for (int mi = 0; mi < 2; mi++)
#pragma unroll
            for (int rg = 0; rg < 4; rg++) {
                int row = mi * 16 + quad * 4 + rg;
                u16 h, l; split2(acc[mi][rg], h, l);
                a3h[row * 132 + col] = h;
                a3l[row * 132 + col] = l;
            }
    }
    __syncthreads();
    // Ph8: GEMM3 + pool (M=32, N=256, K=128), W3 frags double-buffered; direct P write
    {
        int colb = wave * 32;
        f32x4 acc[2][2] = {{{0.f,0.f,0.f,0.f},{0.f,0.f,0.f,0.f}},
                           {{0.f,0.f,0.f,0.f},{0.f,0.f,0.f,0.f}}};
        short8 cwh[2], cwl[2], nwh[2], nwl[2];
#pragma unroll
        for (int ni = 0; ni < 2; ni++) {
            size_t o = (size_t)(colb + ni * 16 + l15) * 128 + quad * 8;
            cwh[ni] = *(const short8*)(W3h + o);
            cwl[ni] = *(const short8*)(W3l + o);
        }
#pragma unroll
        for (int ch = 0; ch < 4; ch++) {
            if (ch < 3) {
#pragma unroll
                for (int ni = 0; ni < 2; ni++) {
                    size_t o = (size_t)(colb + ni * 16 + l15) * 128 + (ch + 1) * 32 + quad * 8;
                    nwh[ni] = *(const short8*)(W3h + o);
                    nwl[ni] = *(const short8*)(W3l + o);
                }
            }
            short8 ah[2], al[2];
#pragma unroll
            for (int mi = 0; mi < 2; mi++) {
                ah[mi] = ld8(&a3h[(mi * 16 + l15) * 132 + ch * 32 + quad * 8]);
                al[mi] = ld8(&a3l[(mi * 16 + l15) * 132 + ch * 32 + quad * 8]);
            }
#pragma unroll
            for (int mi = 0; mi < 2; mi++)
#pragma unroll
                for (int ni = 0; ni < 2; ni++) {
                    acc[mi][ni] = MFMA(ah[mi], cwh[ni], acc[mi][ni]);
                    acc[mi][ni] = MFMA(al[mi], cwh[ni], acc[mi][ni]);
                    acc[mi][ni] = MFMA(ah[mi], cwl[ni], acc[mi][ni]);
                }
            if (ch < 3) {
#pragma unroll
                for (int ni = 0; ni < 2; ni++) { cwh[ni] = nwh[ni]; cwl[ni] = nwl[ni]; }
            }
        }
#pragma unroll
        for (int ni = 0; ni < 2; ni++) {
            int col = colb + ni * 16 + l15;
            float bb = b3[col];
            float p = 0.f;
#pragma unroll
            for (int mi = 0; mi < 2; mi++)
#pragma unroll
                for (int rg = 0; rg < 4; rg++) {
                    int row = mi * 16 + quad * 4 + rg;
                    if (row < 30) p += fmaxf(acc[mi][ni][rg] + bb, 0.f);
                }
            p += __shfl_down(p, 32);
            p += __shfl_down(p, 16);
            if (lane < 16)
                P[(size_t)g * 256 + colb + ni * 16 + lane] = p * (1.0f / 30.0f);
        }
    }
}

// ---------------- cell1: relu(cf @ Wc1 + bc1), fp32 input split in-LDS ----------------
// grid 256 blocks x 32 rows; K=1000 padded 1024, staged in 128-chunks.
__global__ __launch_bounds__(256) void k_cell(const float* __restrict__ cf,
        const u16* __restrict__ Wth, const u16* __restrict__ Wtl,
        const float* __restrict__ bias, float* __restrict__ Y) {
    __shared__ __align__(16) u16 Xh[32 * 136];
    __shared__ __align__(16) u16 Xl[32 * 136];
    int t = threadIdx.x;
    int row0 = blockIdx.x * 32;
    int wave = t >> 6, lane = t & 63, quad = lane >> 4, l15 = lane & 15;
    f32x4 acc[2][2] = {{{0.f,0.f,0.f,0.f},{0.f,0.f,0.f,0.f}},
                       {{0.f,0.f,0.f,0.f},{0.f,0.f,0.f,0.f}}};
    for (int ko = 0; ko < 8; ko++) {
        // stage 32 rows x 128 cols (fp32 -> split)
#pragma unroll
        for (int ii = 0; ii < 4; ii++) {
            int i = t + ii * 256;          // float4 slot
            int r = i >> 5, c4 = i & 31;
            int col = ko * 128 + c4 * 4;
            float4 v = {0.f, 0.f, 0.f, 0.f};
            if (col < 1000) v = *(const float4*)(cf + (size_t)(row0 + r) * 1000 + col);
            float vv[4] = {v.x, v.y, v.z, v.w};
#pragma unroll
            for (int j = 0; j < 4; j++) {
                u16 h, l; split2(vv[j], h, l);
                Xh[r * 136 + c4 * 4 + j] = h;
                Xl[r * 136 + c4 * 4 + j] = l;
            }
        }
        __syncthreads();
#pragma unroll
        for (int kk = 0; kk < 4; kk++) {
            int klo = kk * 32 + quad * 8;
            short8 ah[2], al[2];
#pragma unroll
            for (int mi = 0; mi < 2; mi++) {
                ah[mi] = ld8(&Xh[(mi * 16 + l15) * 136 + klo]);
                al[mi] = ld8(&Xl[(mi * 16 + l15) * 136 + klo]);
            }
#pragma unroll
            for (int ni = 0; ni < 2; ni++) {
                int col = wave * 32 + ni * 16 + l15;
                size_t o = (size_t)col * 1024 + ko * 128 + kk * 32 + quad * 8;
                short8 bh = *(const short8*)(Wth + o);
                short8 bl = *(const short8*)(Wtl + o);
#pragma unroll
                for (int mi = 0; mi < 2; mi++) {
                    acc[mi][ni] = MFMA(ah[mi], bh, acc[mi][ni]);
                    acc[mi][ni] = MFMA(al[mi], bh, acc[mi][ni]);
                    acc[mi][ni] = MFMA(ah[mi], bl, acc[mi][ni]);
                }
            }
        }
        __syncthreads();
    }
#pragma unroll
    for (int ni = 0; ni < 2; ni++) {
        int col = wave * 32 + ni * 16 + l15;
        float bv = bias[col];
#pragma unroll
        for (int mi = 0; mi < 2; mi++)
#pragma unroll
            for (int rg = 0; rg < 4; rg++) {
                int row = row0 + mi * 16 + quad * 4 + rg;
                Y[(size_t)row * 128 + col] = fmaxf(acc[mi][ni][rg] + bv, 0.f);
            }
    }
}

// ---------------- fused tail: drug + cell2 + combiner head, 4 graphs/block ----------------
__global__ __launch_bounds__(256) void k_tail(const float* __restrict__ pooled,
        const float* __restrict__ cell1,
        const float* __restrict__ Wd, const float* __restrict__ bd,
        const float* __restrict__ Wc2, const float* __restrict__ bc2,
        const float* __restrict__ Wm1, const float* __restrict__ bm1,
        const float* __restrict__ Wm2, const float* __restrict__ bm2,
        const float* __restrict__ Wo, const float* __restrict__ bo,
        float* __restrict__ out) {
    __shared__ float pr[1024];
    __shared__ float c1[512];
    __shared__ float dz[512];
    __shared__ float z1f[256];
    __shared__ float z2f[128];
    int t = threadIdx.x;
    int g0 = blockIdx.x * 4;
    int gl = t >> 6, c = t & 63;
    ((float4*)pr)[t] = ((const float4*)(pooled + (size_t)g0 * 256))[t];
    if (t < 128) ((float4*)c1)[t] = ((const float4*)(cell1 + (size_t)g0 * 128))[t];
    __syncthreads();
    float s = bd[c];
#pragma unroll 8
    for (int k = 0; k < 256; k++) s += pr[gl * 256 + k] * Wd[k * 64 + c];
    dz[gl * 128 + c] = s;
    float s2 = bc2[c];
#pragma unroll 8
    for (int k = 0; k < 128; k++) s2 += c1[gl * 128 + k] * Wc2[k * 64 + c];
    dz[gl * 128 + 64 + c] = s2;
    __syncthreads();
    float s3 = bm1[c];
#pragma unroll 8
    for (int k = 0; k < 128; k++) s3 += dz[gl * 128 + k] * Wm1[k * 64 + c];
    z1f[gl * 64 + c] = fmaxf(s3, 0.f);
    __syncthreads();
    if (c < 32) {
        float s4 = bm2[c];
#pragma unroll 8
        for (int k = 0; k < 64; k++) s4 += z1f[gl * 64 + k] * Wm2[k * 32 + c];
        z2f[gl * 32 + c] = fmaxf(s4, 0.f);
    }
    __syncthreads();
    float v = (c < 32) ? z2f[gl * 32 + c] * Wo[c] : 0.f;
#pragma unroll
    for (int off = 32; off > 0; off >>= 1) v += __shfl_down(v, off);
    if (c == 0) out[g0 + gl] = v + bo[0];
}

// ---------------- launch ----------------

extern "C" void kernel_launch(void* const* d_in, const int* in_sizes, int n_in,
                              void* d_out, int out_size, void* d_ws, size_t ws_size,
                              hipStream_t stream) {
    const float* x   = (const float*)d_in[0];
    const int*   ei  = (const int*)d_in[1];
    const float* cf  = (const float*)d_in[3];
    const float* W1  = (const float*)d_in[4];
    const float* b1  = (const float*)d_in[5];
    const float* W2  = (const float*)d_in[6];
    const float* b2  = (const float*)d_in[7];
    const float* W3  = (const float*)d_in[8];
    const float* b3  = (const float*)d_in[9];
    const float* Wd  = (const float*)d_in[10];
    const float* bd  = (const float*)d_in[11];
    const float* Wc1 = (const float*)d_in[12];
    const float* bc1 = (const float*)d_in[13];
    const float* Wc2 = (const float*)d_in[14];
    const float* bc2 = (const float*)d_in[15];
    const float* Wm1 = (const float*)d_in[16];
    const float* bm1 = (const float*)d_in[17];
    const float* Wm2 = (const float*)d_in[18];
    const float* bm2 = (const float*)d_in[19];
    const float* Wo  = (const float*)d_in[20];
    const float* bo  = (const float*)d_in[21];
    float* out = (float*)d_out;

    const int E = in_sizes[1] / 2;     // 1,000,000
    const int B = in_sizes[3] / 1000;  // 8192

    char* w = (char*)d_ws;
    auto carve = [&](size_t bytes) { void* p = (void*)w; w += (bytes + 255) & ~(size_t)255; return p; };
    unsigned* A32 = (unsigned*)carve((size_t)B * 960 * 2);   // u16 counts, 15.7 MB
    float* pooled = (float*)carve((size_t)B * 256 * 4);
    float* cell1  = (float*)carve((size_t)B * 128 * 4);
    u16* W1th = (u16*)carve(64 * 96 * 2);     u16* W1tl = (u16*)carve(64 * 96 * 2);
    u16* W2th = (u16*)carve(128 * 64 * 2);    u16* W2tl = (u16*)carve(128 * 64 * 2);
    u16* W3th = (u16*)carve(256 * 128 * 2);   u16* W3tl = (u16*)carve(256 * 128 * 2);
    u16* Wc1th = (u16*)carve(128 * 1024 * 2); u16* Wc1tl = (u16*)carve(128 * 1024 * 2);

    auto g1 = [](int n) { return (n + 255) / 256; };

    // prep: packed u16 adjacency count matrices
    k_zero4<<<g1(B * 120), 256, 0, stream>>>((int4*)A32, B * 120);
    k_cnt<<<g1(E), 256, 0, stream>>>(ei, A32, E);

    // weight pre-split (hi/lo bf16, transposed [F][Kp])
    k_split_t<<<g1(64 * 96), 256, 0, stream>>>(W1, W1th, W1tl, 78, 64, 96);
    k_split_t<<<g1(128 * 64), 256, 0, stream>>>(W2, W2th, W2tl, 64, 128, 64);
    k_split_t<<<g1(256 * 128), 256, 0, stream>>>(W3, W3th, W3tl, 128, 256, 128);
    k_split_t<<<g1(128 * 1024), 256, 0, stream>>>(Wc1, Wc1th, Wc1tl, 1000, 128, 1024);

    // fused GCN pipeline: one block per graph
    k_node<<<B, 512, 0, stream>>>(x, A32,
                                  W1th, W1tl, W2th, W2tl, W3th, W3tl,
                                  b1, b2, b3, pooled);

    // cell MLP layer 1 (MFMA, fp32 input split in-LDS)
    k_cell<<<B / 32, 256, 0, stream>>>(cf, Wc1th, Wc1tl, bc1, cell1);

    // fused tail: drug embed + cell2 + combiner head
    k_tail<<<B / 4, 256, 0, stream>>>(pooled, cell1, Wd, bd, Wc2, bc2,
                                      Wm1, bm1, Wm2, bm2, Wo, bo, out);
}